// Round 4
// baseline (304.278 us; speedup 1.0000x reference)
//
#include <hip/hip_runtime.h>
#include <math.h>

#define D_MODEL 1024
#define D_INT   64
#define KW      32
#define L_SEQ   4096
#define SUBHEADS 5
#define HEADS   14
#define M_ROWS  8192
#define N_CAT   896
#define NQK     320          // SUBHEADS*64

typedef unsigned short us;
typedef unsigned int   uu;
typedef __attribute__((ext_vector_type(4))) unsigned int uu4;
typedef __attribute__((ext_vector_type(8))) short bf16x8_t;
typedef __attribute__((ext_vector_type(4))) float f32x4_t;

__device__ __forceinline__ float u2f(uu u) {
    float f; __builtin_memcpy(&f, &u, 4); return f;
}
__device__ __forceinline__ float blo(uu u) { return u2f(u << 16); }
__device__ __forceinline__ float bhi(uu u) { return u2f(u & 0xffff0000u); }
__device__ __forceinline__ us f2b(float f) {
    uu u; __builtin_memcpy(&u, &f, 4);
    u += 0x7fffu + ((u >> 16) & 1u);
    return (us)(u >> 16);
}
__device__ __forceinline__ uu pack2(float a, float b) {
    return (uu)f2b(a) | ((uu)f2b(b) << 16);
}
// hardware packed cvt: RNE, bit-identical to pack2
__device__ __forceinline__ uu cvtpk(float a, float b) {
    uu r;
    asm("v_cvt_pk_bf16_f32 %0, %1, %2" : "=v"(r) : "v"(a), "v"(b));
    return r;
}
__device__ __forceinline__ void load16(void* lds, const void* g) {
    __builtin_amdgcn_global_load_lds(
        (const __attribute__((address_space(1))) unsigned int*)g,
        (__attribute__((address_space(3))) unsigned int*)lds, 16, 0, 0);
}
__device__ __forceinline__ int dil_of_sub(int s) {
    return (s <= 1) ? 1 : (1 << (s - 1));   // 1,1,2,4,8
}
__device__ __forceinline__ int hstart_of_sub(int s) {
    return (s == 0) ? 0 : (s == 1) ? 5 : (s == 2) ? 10 : (s == 3) ? 12 : 13;
}
__device__ __forceinline__ int hcount_of_sub(int s) {
    return (s <= 1) ? 5 : (s == 2) ? 2 : 1;
}

// ---------------------------------------------------------------------------
// Prep mega-kernel: grid-stride q/k/v casts (blocks [0,1536)) + 32x32 weight
// transpose-casts (blocks [1536,3968)).
// ---------------------------------------------------------------------------
#define CAST_BLK 1536
__global__ __launch_bounds__(256)
void prep_kernel(const float4* __restrict__ q, const float4* __restrict__ k,
                 const float4* __restrict__ v,
                 const float* __restrict__ Wq, const float* __restrict__ Wk,
                 const float* __restrict__ Wv, const float* __restrict__ Wc,
                 us* __restrict__ Xq, us* __restrict__ Xk, us* __restrict__ Xv,
                 us* __restrict__ Wqt, us* __restrict__ Wkt,
                 us* __restrict__ Wvt, us* __restrict__ Wct)
{
    __shared__ float t[32][33];
    const int tid = threadIdx.x;
    const int b = blockIdx.x;

    if (b < CAST_BLK) {
        const int arr = b >> 9;               // 0,1,2
        const int blk = b & 511;
        const float4* s = (arr == 0) ? q : (arr == 1) ? k : v;
        uu4* d = (uu4*)((arr == 0) ? Xq : (arr == 1) ? Xk : Xv);
        const int tg = blk * 256 + tid;       // 0..131071
#pragma unroll
        for (int it = 0; it < 8; it++) {
            const int i = tg + it * 131072;
            float4 x0 = s[2 * i];
            float4 x1 = s[2 * i + 1];
            uu4 o;
            o.x = cvtpk(x0.x, x0.y); o.y = cvtpk(x0.z, x0.w);
            o.z = cvtpk(x1.x, x1.y); o.w = cvtpk(x1.z, x1.w);
            d[i] = o;
        }
        return;
    }

    int g = b - CAST_BLK;
    const float* S; us* D; int K, N;
    if (g < 640) {
        if (g < 320) { S = Wq; D = Wqt; } else { S = Wk; D = Wkt; g -= 320; }
        K = 1024; N = 64;
    } else if (g < 1536) {
        g -= 640; S = Wv; D = Wvt; K = 1024; N = 64;
    } else {
        g -= 1536; S = Wc; D = Wct; K = 896; N = 1024;
    }
    const int nkx = K >> 5;
    const int kx = g % nkx;
    const int rest = g / nkx;
    const int ny = rest % (N >> 5);
    const int z  = rest / (N >> 5);
    const int k0 = kx * 32, n0 = ny * 32;
    S += (size_t)z * K * N;
    D += (size_t)z * K * N;
    const int tx = tid & 31, ty = tid >> 5;
#pragma unroll
    for (int r = 0; r < 32; r += 8)
        t[r + ty][tx] = S[(size_t)(k0 + r + ty) * N + n0 + tx];
    __syncthreads();
#pragma unroll
    for (int r = 0; r < 32; r += 8)
        D[(size_t)(n0 + r + ty) * K + k0 + tx] = f2b(t[tx][r + ty]);
}

// ---------------------------------------------------------------------------
// 128x64-tile GEMM core (BK=64, XOR-swizzled LDS, global_load_lds 16B)
// ---------------------------------------------------------------------------
__device__ __forceinline__
void gemm64_core(const us* __restrict__ A, const us* __restrict__ Bt,
                 const float* __restrict__ bias, us* __restrict__ C,
                 int K, int ldC, int row0, int col0, us* As, us* Bs)
{
    const int tid = threadIdx.x, w = tid >> 6, lane = tid & 63;
    const int m = lane & 15, quad = lane >> 4;
    const int sr = lane >> 3;
    const int scs = (lane & 7) ^ sr;

    f32x4_t z4 = {0.f, 0.f, 0.f, 0.f};
    f32x4_t acc[2][4] = {{z4, z4, z4, z4}, {z4, z4, z4, z4}};

    for (int k0 = 0; k0 < K; k0 += 64) {
#pragma unroll
        for (int p = 0; p < 4; p++) {
            const int r = w * 32 + p * 8 + sr;
            load16(&As[(w * 32 + p * 8) * 64], A + (size_t)(row0 + r) * K + k0 + scs * 8);
        }
#pragma unroll
        for (int p = 0; p < 2; p++) {
            const int r = w * 16 + p * 8 + sr;
            load16(&Bs[(w * 16 + p * 8) * 64], Bt + (size_t)(col0 + r) * K + k0 + scs * 8);
        }
        __syncthreads();
#pragma unroll
        for (int ks = 0; ks < 2; ks++) {
            const int slot = ((ks * 4 + quad) ^ (m & 7)) * 8;
            bf16x8_t a0 = *(const bf16x8_t*)&As[(w * 32 + m) * 64 + slot];
            bf16x8_t a1 = *(const bf16x8_t*)&As[(w * 32 + 16 + m) * 64 + slot];
#pragma unroll
            for (int t = 0; t < 4; t++) {
                bf16x8_t bb = *(const bf16x8_t*)&Bs[(t * 16 + m) * 64 + slot];
                acc[0][t] = __builtin_amdgcn_mfma_f32_16x16x32_bf16(a0, bb, acc[0][t], 0, 0, 0);
                acc[1][t] = __builtin_amdgcn_mfma_f32_16x16x32_bf16(a1, bb, acc[1][t], 0, 0, 0);
            }
        }
        __syncthreads();
    }

#pragma unroll
    for (int tm = 0; tm < 2; tm++) {
        const int rbase = row0 + w * 32 + tm * 16 + quad * 4;
#pragma unroll
        for (int t = 0; t < 4; t++) {
            const int col = col0 + t * 16 + m;
            const float bi = bias[col];
#pragma unroll
            for (int r = 0; r < 4; r++)
                C[(size_t)(rbase + r) * ldC + col] = f2b(acc[tm][t][r] + bi);
        }
    }
}

// ---------------------------------------------------------------------------
// 128x128-tile core (m97 structure)
// ---------------------------------------------------------------------------
__device__ __forceinline__
void gemm128_core(const us* __restrict__ A, const us* __restrict__ Bt,
                  const float* __restrict__ bias, void* __restrict__ Cv,
                  int K, int ldC, int outBf16, int row0, int col0,
                  us* As, us* Bs)
{
    const int tid = threadIdx.x, w = tid >> 6, lane = tid & 63;
    const int m = lane & 15, quad = lane >> 4;
    const int sr = lane >> 3;
    const int scs = (lane & 7) ^ sr;
    const int mrow0 = (w & 1) * 64, ncol0 = (w >> 1) * 64;

    f32x4_t z = {0.f, 0.f, 0.f, 0.f};
    f32x4_t acc[4][4] = {{z,z,z,z},{z,z,z,z},{z,z,z,z},{z,z,z,z}};

    for (int k0 = 0; k0 < K; k0 += 64) {
#pragma unroll
        for (int p = 0; p < 4; p++) {
            const int r = w * 32 + p * 8 + sr;
            load16(&As[(w * 32 + p * 8) * 64], A  + (size_t)(row0 + r) * K + k0 + scs * 8);
            load16(&Bs[(w * 32 + p * 8) * 64], Bt + (size_t)(col0 + r) * K + k0 + scs * 8);
        }
        __syncthreads();
#pragma unroll
        for (int ks = 0; ks < 2; ks++) {
            const int slot = ((ks * 4 + quad) ^ (m & 7)) * 8;
            bf16x8_t a[4], b[4];
#pragma unroll
            for (int t = 0; t < 4; t++) {
                a[t] = *(const bf16x8_t*)&As[(mrow0 + t * 16 + m) * 64 + slot];
                b[t] = *(const bf16x8_t*)&Bs[(ncol0 + t * 16 + m) * 64 + slot];
            }
#pragma unroll
            for (int i = 0; i < 4; i++)
#pragma unroll
                for (int j = 0; j < 4; j++)
                    acc[i][j] = __builtin_amdgcn_mfma_f32_16x16x32_bf16(a[i], b[j], acc[i][j], 0, 0, 0);
        }
        __syncthreads();
    }

#pragma unroll
    for (int i = 0; i < 4; i++) {
        const int rbase = row0 + mrow0 + i * 16 + quad * 4;
        if (outBf16) {
            us* Cb = (us*)Cv;
#pragma unroll
            for (int j = 0; j < 4; j++) {
                const int col = col0 + ncol0 + j * 16 + m;
                const float bi = bias[col];
#pragma unroll
                for (int r = 0; r < 4; r++)
                    Cb[(size_t)(rbase + r) * ldC + col] = f2b(acc[i][j][r] + bi);
            }
        } else {
            float* Cb = (float*)Cv;
#pragma unroll
            for (int j = 0; j < 4; j++) {
                const int col = col0 + ncol0 + j * 16 + m;
                const float bi = bias[col];
#pragma unroll
                for (int r = 0; r < 4; r++)
                    Cb[(size_t)(rbase + r) * ldC + col] = acc[i][j][r] + bi;
            }
        }
    }
}

// ---------------------------------------------------------------------------
// Fused projections: v (448 128x128 blocks first), then q+k (640 128x64).
// ---------------------------------------------------------------------------
__global__ __launch_bounds__(256)
void proj_kernel(const us* __restrict__ Xq, const us* __restrict__ Xk,
                 const us* __restrict__ Xv,
                 const us* __restrict__ Wqt, const us* __restrict__ Wkt,
                 const us* __restrict__ Wvt,
                 const float* __restrict__ bq, const float* __restrict__ bk,
                 const float* __restrict__ bv,
                 us* __restrict__ qbuf, us* __restrict__ kbuf,
                 us* __restrict__ vbuf)
{
    __shared__ us As[128 * 64];
    __shared__ us Bs[128 * 64];
    const int b = blockIdx.x;
    if (b < 448) {
        const int bx = b & 63, cy = b >> 6;          // 64 x 7
        gemm128_core(Xv, Wvt, bv, vbuf, D_MODEL, N_CAT, 1,
                     bx << 7, cy << 7, As, Bs);
    } else {
        const int idx = b - 448;
        const int bx = idx & 63;
        const int rest = idx >> 6;                   // 0..9
        const int cy = rest % 5, z = rest / 5;
        gemm64_core(z ? Xk : Xq, z ? Wkt : Wqt, z ? bk : bq,
                    z ? kbuf : qbuf, D_MODEL, NQK,
                    bx << 7, cy << 6, As, Bs);
    }
}

// out gemm: [8192][896] bf16 @ [896][1024] -> fp32
__global__ __launch_bounds__(256)
void gemm_out(const us* __restrict__ ab, const us* __restrict__ Wct,
              const float* __restrict__ bc, float* __restrict__ out)
{
    __shared__ us As[128 * 64];
    __shared__ us Bs[128 * 64];
    gemm128_core(ab, Wct, bc, out, N_CAT, D_MODEL, 0,
                 (int)(blockIdx.x << 7), (int)(blockIdx.y << 7), As, Bs);
}

// ---------------------------------------------------------------------------
// FUSED attention kernel: one block = (64-row slab, subhead).
//   phase S: stage k/q (uu4), compute scores -> sab (LDS, f32, stride 36)
//   then loop heads of this subhead: stage vslab (aliases kslab),
//   resample+softmax -> atn, PV -> ab.
// sab persists across heads (separate atn buffer). atn rows wave-private:
// no barrier between resample and PV. vslab stage is placed BEFORE the
// resample so its latency hides under the resample VALU work.
// grid (128, nsub). ROWS = max W = 64+31*d.
// ---------------------------------------------------------------------------
template<int ROWS>
__global__ __launch_bounds__(256)
void attn_kernel(const us* __restrict__ qb, const us* __restrict__ kb,
                 const us* __restrict__ vb,
                 const float* __restrict__ Ws, const float* __restrict__ bs,
                 us* __restrict__ ab, int sbase)
{
    __shared__ uu    kq[ROWS * 36 + 64 * 32];  // kslab+qslab; vslab aliases kslab
    __shared__ float sab[64 * 36];             // scores, persist across heads
    __shared__ float atn[64 * 36];             // per-head attention weights

    uu* kslab = kq;                // [ROWS][36] (score phase)
    uu* qslab = kq + ROWS * 36;    // [64][32]   (score phase)
    uu* vslab = kq;                // [ROWS][36] (head phase, aliases kslab)

    const int tid  = threadIdx.x;
    const int wave = tid >> 6;
    const int lane = tid & 63;
    const int j    = lane & 31;
    const int half = lane >> 5;
    const int s    = sbase + blockIdx.y;
    const int d    = dil_of_sub(s);
    const int ml0  = blockIdx.x * 64;
    const int l0   = ml0 & 4095;
    const int bm   = ml0 - l0;
    const int W    = 64 + 31 * d;

    // ---- stage k (W x 32 uu) + q (64 x 32 uu), vectorized uu4 ----
    const uu4* kg4 = (const uu4*)kb;   // row stride 40 uu4
    const uu4* qg4 = (const uu4*)qb;   // row stride 40 uu4
    for (int idx = tid; idx < W * 8; idx += 256) {
        int r = idx >> 3, c4 = idx & 7;
        int src = l0 - 16 * d + r;
        src = src < 0 ? 0 : (src > 4095 ? 4095 : src);
        *(uu4*)&kslab[r * 36 + c4 * 4] = kg4[(size_t)(bm + src) * 40 + s * 8 + c4];
    }
    for (int idx = tid; idx < 64 * 8; idx += 256) {
        int r = idx >> 3, c4 = idx & 7;
        *(uu4*)&qslab[r * 32 + c4 * 4] = qg4[(size_t)(ml0 + r) * 40 + s * 8 + c4];
    }
    __syncthreads();

    // ---- scores -> sab ----
#pragma unroll
    for (int i = 0; i < 8; i++) {
        const int p = wave * 16 + i * 2 + half;
        const uu4* k4 = (const uu4*)&kslab[(p + j * d) * 36];
        const uu4* q4 = (const uu4*)&qslab[p * 32];
        float acc = 0.f;
#pragma unroll
        for (int q = 0; q < 8; q++) {
            uu4 kd = k4[q];
            uu4 qd = q4[q];
            acc = fmaf(blo(kd.x), blo(qd.x), acc); acc = fmaf(bhi(kd.x), bhi(qd.x), acc);
            acc = fmaf(blo(kd.y), blo(qd.y), acc); acc = fmaf(bhi(kd.y), bhi(qd.y), acc);
            acc = fmaf(blo(kd.z), blo(qd.z), acc); acc = fmaf(bhi(kd.z), bhi(qd.z), acc);
            acc = fmaf(blo(kd.w), blo(qd.w), acc); acc = fmaf(bhi(kd.w), bhi(qd.w), acc);
        }
        sab[p * 36 + j] = acc * 0.125f;
    }
    __syncthreads();    // kslab reads done -> safe to overwrite with vslab

    const int h0 = hstart_of_sub(s);
    const int hc = hcount_of_sub(s);
    const uu4* vg4 = (const uu4*)vb;   // row stride 112 uu4

    for (int hh = h0; hh < h0 + hc; hh++) {
        // ---- stage vslab for this head ----
        for (int idx = tid; idx < W * 8; idx += 256) {
            int r = idx >> 3, c4 = idx & 7;
            int src = l0 - 16 * d + r;
            src = src < 0 ? 0 : (src > 4095 ? 4095 : src);
            *(uu4*)&vslab[r * 36 + c4 * 4] = vg4[(size_t)(bm + src) * 112 + hh * 8 + c4];
        }
        float wsr[32];
#pragma unroll
        for (int k = 0; k < 32; k++) wsr[k] = Ws[(size_t)hh * 1024 + k * 32 + j];
        const float bsv = bs[hh * 32 + j];

        // ---- resample + softmax -> atn (independent of vslab; overlaps) ----
#pragma unroll
        for (int i = 0; i < 8; i++) {
            const int p = wave * 16 + i * 2 + half;
            const float4* s4 = (const float4*)&sab[p * 36];
            float acc = bsv;
#pragma unroll
            for (int q = 0; q < 8; q++) {
                float4 v = s4[q];
                acc = fmaf(v.x, wsr[q * 4 + 0], acc);
                acc = fmaf(v.y, wsr[q * 4 + 1], acc);
                acc = fmaf(v.z, wsr[q * 4 + 2], acc);
                acc = fmaf(v.w, wsr[q * 4 + 3], acc);
            }
            float mx = acc;
#pragma unroll
            for (int off = 16; off > 0; off >>= 1) mx = fmaxf(mx, __shfl_xor(mx, off, 64));
            float ex = __expf(acc - mx);
            float sum = ex;
#pragma unroll
            for (int off = 16; off > 0; off >>= 1) sum += __shfl_xor(sum, off, 64);
            atn[p * 36 + j] = ex / sum;
        }
        __syncthreads();   // vslab fully staged; atn rows wave-private

        // ---- PV: 8 positions per pass ----
        const int o = lane >> 3;     // position octet
        const int c = lane & 7;      // channel chunk (4 dwords = 8 channels)
#pragma unroll
        for (int pass = 0; pass < 2; pass++) {
            const int p  = wave * 16 + pass * 8 + o;
            const int ml = ml0 + p;
            float a0 = 0.f, a1 = 0.f, a2 = 0.f, a3 = 0.f;
            float a4 = 0.f, a5 = 0.f, a6 = 0.f, a7 = 0.f;
#pragma unroll
            for (int mm = 0; mm < 32; mm++) {
                const float at = atn[p * 36 + mm];
                uu4 vd = *(const uu4*)&vslab[(p + mm * d) * 36 + c * 4];
                a0 = fmaf(blo(vd.x), at, a0); a1 = fmaf(bhi(vd.x), at, a1);
                a2 = fmaf(blo(vd.y), at, a2); a3 = fmaf(bhi(vd.y), at, a3);
                a4 = fmaf(blo(vd.z), at, a4); a5 = fmaf(bhi(vd.z), at, a5);
                a6 = fmaf(blo(vd.w), at, a6); a7 = fmaf(bhi(vd.w), at, a7);
            }
            uu4 od;
            od.x = pack2(a0, a1); od.y = pack2(a2, a3);
            od.z = pack2(a4, a5); od.w = pack2(a6, a7);
            *(uu4*)&((uu*)ab)[(size_t)ml * 448 + hh * 32 + c * 4] = od;
        }
        __syncthreads();   // PV done before next head's vslab overwrite
    }
}

// ---------------------------------------------------------------------------
extern "C" void kernel_launch(void* const* d_in, const int* in_sizes, int n_in,
                              void* d_out, int out_size, void* d_ws, size_t ws_size,
                              hipStream_t stream)
{
    const float* query = (const float*)d_in[0];
    const float* key   = (const float*)d_in[1];
    const float* value = (const float*)d_in[2];
    const float* Wq    = (const float*)d_in[3];
    const float* bq    = (const float*)d_in[4];
    const float* Wk    = (const float*)d_in[5];
    const float* bk    = (const float*)d_in[6];
    const float* Wv    = (const float*)d_in[7];
    const float* bv    = (const float*)d_in[8];
    const float* Ws    = (const float*)d_in[9];
    const float* bs    = (const float*)d_in[10];
    const float* Wc    = (const float*)d_in[11];
    const float* bc    = (const float*)d_in[12];
    float* out = (float*)d_out;

    // workspace carve (bf16 elements). ab aliases Xq (Xq dead after q gemm).
    us* w = (us*)d_ws;
    us* Xq  = w;                          // 8192*1024
    us* ab  = w;                          // 8192*896 (alias of Xq)
    us* Xk  = Xq  + (size_t)M_ROWS * D_MODEL;
    us* Xv  = Xk  + (size_t)M_ROWS * D_MODEL;
    us* Wqt = Xv  + (size_t)M_ROWS * D_MODEL;           // [320][1024]
    us* Wkt = Wqt + (size_t)SUBHEADS * D_INT * D_MODEL;
    us* Wvt = Wkt + (size_t)SUBHEADS * D_INT * D_MODEL; // [896][1024]
    us* Wct = Wvt + (size_t)HEADS * D_INT * D_MODEL;    // [1024][896]
    us* qbuf = Wct + (size_t)D_MODEL * N_CAT;           // [8192][320]
    us* kbuf = qbuf + (size_t)M_ROWS * NQK;
    us* vbuf = kbuf + (size_t)M_ROWS * NQK;             // [8192][896]

    dim3 blk(256);

    // prep: grid-stride q/k/v casts + weight transposes in one launch
    prep_kernel<<<dim3(CAST_BLK + 2432), blk, 0, stream>>>(
        (const float4*)query, (const float4*)key, (const float4*)value,
        Wq, Wk, Wv, Wc, Xq, Xk, Xv, Wqt, Wkt, Wvt, Wct);

    // fused q/k/v projections (bf16 A via global_load_lds): 1088 blocks
    proj_kernel<<<dim3(1088), blk, 0, stream>>>(
        Xq, Xk, Xv, Wqt, Wkt, Wvt, bq, bk, bv, qbuf, kbuf, vbuf);

    // fused scores+heads:
    //   A: subheads 0,1 (d=1, W=95, 5 heads each) — uniform blocks
    //   B: subheads 2,3,4 (W=126/188/312, heads 2/1/1)
    attn_kernel<95><<<dim3(M_ROWS / 64, 2), blk, 0, stream>>>(
        qbuf, kbuf, vbuf, Ws, bs, ab, 0);
    attn_kernel<312><<<dim3(M_ROWS / 64, 3), blk, 0, stream>>>(
        qbuf, kbuf, vbuf, Ws, bs, ab, 2);

    // out gemm: [8192][896] @ [896][1024] -> fp32 (128x128 tile)
    gemm_out<<<dim3(M_ROWS / 128, D_MODEL / 128), blk, 0, stream>>>(
        ab, Wct, bc, out);
}

// Round 5
// 284.499 us; speedup vs baseline: 1.0695x; 1.0695x over previous
//
#include <hip/hip_runtime.h>
#include <math.h>

#define D_MODEL 1024
#define D_INT   64
#define KW      32
#define L_SEQ   4096
#define SUBHEADS 5
#define HEADS   14
#define M_ROWS  8192
#define N_CAT   896
#define NQK     320          // SUBHEADS*64

typedef unsigned short us;
typedef unsigned int   uu;
typedef __attribute__((ext_vector_type(4))) unsigned int uu4;
typedef __attribute__((ext_vector_type(8))) short bf16x8_t;
typedef __attribute__((ext_vector_type(4))) float f32x4_t;

__device__ __forceinline__ float u2f(uu u) {
    float f; __builtin_memcpy(&f, &u, 4); return f;
}
__device__ __forceinline__ float blo(uu u) { return u2f(u << 16); }
__device__ __forceinline__ float bhi(uu u) { return u2f(u & 0xffff0000u); }
__device__ __forceinline__ us f2b(float f) {
    uu u; __builtin_memcpy(&u, &f, 4);
    u += 0x7fffu + ((u >> 16) & 1u);
    return (us)(u >> 16);
}
__device__ __forceinline__ uu pack2(float a, float b) {
    return (uu)f2b(a) | ((uu)f2b(b) << 16);
}
// hardware packed cvt: RNE, bit-identical to pack2
__device__ __forceinline__ uu cvtpk(float a, float b) {
    uu r;
    asm("v_cvt_pk_bf16_f32 %0, %1, %2" : "=v"(r) : "v"(a), "v"(b));
    return r;
}
__device__ __forceinline__ void load16(void* lds, const void* g) {
    __builtin_amdgcn_global_load_lds(
        (const __attribute__((address_space(1))) unsigned int*)g,
        (__attribute__((address_space(3))) unsigned int*)lds, 16, 0, 0);
}
__device__ __forceinline__ int subhead_of(int h) {
    return (h < 5) ? 0 : (h < 10) ? 1 : (h < 12) ? 2 : (h == 12) ? 3 : 4;
}
__device__ __forceinline__ int dil_of_sub(int s) {
    return (s <= 1) ? 1 : (1 << (s - 1));   // 1,1,2,4,8
}

// ---------------------------------------------------------------------------
// Prep mega-kernel: grid-stride q/k/v casts (blocks [0,1536)) + 32x32 weight
// transpose-casts (blocks [1536,3968)).
// ---------------------------------------------------------------------------
#define CAST_BLK 1536
__global__ __launch_bounds__(256)
void prep_kernel(const float4* __restrict__ q, const float4* __restrict__ k,
                 const float4* __restrict__ v,
                 const float* __restrict__ Wq, const float* __restrict__ Wk,
                 const float* __restrict__ Wv, const float* __restrict__ Wc,
                 us* __restrict__ Xq, us* __restrict__ Xk, us* __restrict__ Xv,
                 us* __restrict__ Wqt, us* __restrict__ Wkt,
                 us* __restrict__ Wvt, us* __restrict__ Wct)
{
    __shared__ float t[32][33];
    const int tid = threadIdx.x;
    const int b = blockIdx.x;

    if (b < CAST_BLK) {
        const int arr = b >> 9;               // 0,1,2
        const int blk = b & 511;
        const float4* s = (arr == 0) ? q : (arr == 1) ? k : v;
        uu4* d = (uu4*)((arr == 0) ? Xq : (arr == 1) ? Xk : Xv);
        const int tg = blk * 256 + tid;       // 0..131071
#pragma unroll
        for (int it = 0; it < 8; it++) {
            const int i = tg + it * 131072;
            float4 x0 = s[2 * i];
            float4 x1 = s[2 * i + 1];
            uu4 o;
            o.x = cvtpk(x0.x, x0.y); o.y = cvtpk(x0.z, x0.w);
            o.z = cvtpk(x1.x, x1.y); o.w = cvtpk(x1.z, x1.w);
            d[i] = o;
        }
        return;
    }

    int g = b - CAST_BLK;
    const float* S; us* D; int K, N;
    if (g < 640) {
        if (g < 320) { S = Wq; D = Wqt; } else { S = Wk; D = Wkt; g -= 320; }
        K = 1024; N = 64;
    } else if (g < 1536) {
        g -= 640; S = Wv; D = Wvt; K = 1024; N = 64;
    } else {
        g -= 1536; S = Wc; D = Wct; K = 896; N = 1024;
    }
    const int nkx = K >> 5;
    const int kx = g % nkx;
    const int rest = g / nkx;
    const int ny = rest % (N >> 5);
    const int z  = rest / (N >> 5);
    const int k0 = kx * 32, n0 = ny * 32;
    S += (size_t)z * K * N;
    D += (size_t)z * K * N;
    const int tx = tid & 31, ty = tid >> 5;
#pragma unroll
    for (int r = 0; r < 32; r += 8)
        t[r + ty][tx] = S[(size_t)(k0 + r + ty) * N + n0 + tx];
    __syncthreads();
#pragma unroll
    for (int r = 0; r < 32; r += 8)
        D[(size_t)(n0 + r + ty) * K + k0 + tx] = f2b(t[tx][r + ty]);
}

// ---------------------------------------------------------------------------
// 128x64-tile GEMM core (BK=64, XOR-swizzled LDS, global_load_lds 16B)
// ---------------------------------------------------------------------------
__device__ __forceinline__
void gemm64_core(const us* __restrict__ A, const us* __restrict__ Bt,
                 const float* __restrict__ bias, us* __restrict__ C,
                 int K, int ldC, int row0, int col0, us* As, us* Bs)
{
    const int tid = threadIdx.x, w = tid >> 6, lane = tid & 63;
    const int m = lane & 15, quad = lane >> 4;
    const int sr = lane >> 3;
    const int scs = (lane & 7) ^ sr;

    f32x4_t z4 = {0.f, 0.f, 0.f, 0.f};
    f32x4_t acc[2][4] = {{z4, z4, z4, z4}, {z4, z4, z4, z4}};

    for (int k0 = 0; k0 < K; k0 += 64) {
#pragma unroll
        for (int p = 0; p < 4; p++) {
            const int r = w * 32 + p * 8 + sr;
            load16(&As[(w * 32 + p * 8) * 64], A + (size_t)(row0 + r) * K + k0 + scs * 8);
        }
#pragma unroll
        for (int p = 0; p < 2; p++) {
            const int r = w * 16 + p * 8 + sr;
            load16(&Bs[(w * 16 + p * 8) * 64], Bt + (size_t)(col0 + r) * K + k0 + scs * 8);
        }
        __syncthreads();
#pragma unroll
        for (int ks = 0; ks < 2; ks++) {
            const int slot = ((ks * 4 + quad) ^ (m & 7)) * 8;
            bf16x8_t a0 = *(const bf16x8_t*)&As[(w * 32 + m) * 64 + slot];
            bf16x8_t a1 = *(const bf16x8_t*)&As[(w * 32 + 16 + m) * 64 + slot];
#pragma unroll
            for (int t = 0; t < 4; t++) {
                bf16x8_t bb = *(const bf16x8_t*)&Bs[(t * 16 + m) * 64 + slot];
                acc[0][t] = __builtin_amdgcn_mfma_f32_16x16x32_bf16(a0, bb, acc[0][t], 0, 0, 0);
                acc[1][t] = __builtin_amdgcn_mfma_f32_16x16x32_bf16(a1, bb, acc[1][t], 0, 0, 0);
            }
        }
        __syncthreads();
    }

#pragma unroll
    for (int tm = 0; tm < 2; tm++) {
        const int rbase = row0 + w * 32 + tm * 16 + quad * 4;
#pragma unroll
        for (int t = 0; t < 4; t++) {
            const int col = col0 + t * 16 + m;
            const float bi = bias[col];
#pragma unroll
            for (int r = 0; r < 4; r++)
                C[(size_t)(rbase + r) * ldC + col] = f2b(acc[tm][t][r] + bi);
        }
    }
}

// ---------------------------------------------------------------------------
// 128x128-tile core (m97 structure)
// ---------------------------------------------------------------------------
__device__ __forceinline__
void gemm128_core(const us* __restrict__ A, const us* __restrict__ Bt,
                  const float* __restrict__ bias, void* __restrict__ Cv,
                  int K, int ldC, int outBf16, int row0, int col0,
                  us* As, us* Bs)
{
    const int tid = threadIdx.x, w = tid >> 6, lane = tid & 63;
    const int m = lane & 15, quad = lane >> 4;
    const int sr = lane >> 3;
    const int scs = (lane & 7) ^ sr;
    const int mrow0 = (w & 1) * 64, ncol0 = (w >> 1) * 64;

    f32x4_t z = {0.f, 0.f, 0.f, 0.f};
    f32x4_t acc[4][4] = {{z,z,z,z},{z,z,z,z},{z,z,z,z},{z,z,z,z}};

    for (int k0 = 0; k0 < K; k0 += 64) {
#pragma unroll
        for (int p = 0; p < 4; p++) {
            const int r = w * 32 + p * 8 + sr;
            load16(&As[(w * 32 + p * 8) * 64], A  + (size_t)(row0 + r) * K + k0 + scs * 8);
            load16(&Bs[(w * 32 + p * 8) * 64], Bt + (size_t)(col0 + r) * K + k0 + scs * 8);
        }
        __syncthreads();
#pragma unroll
        for (int ks = 0; ks < 2; ks++) {
            const int slot = ((ks * 4 + quad) ^ (m & 7)) * 8;
            bf16x8_t a[4], b[4];
#pragma unroll
            for (int t = 0; t < 4; t++) {
                a[t] = *(const bf16x8_t*)&As[(mrow0 + t * 16 + m) * 64 + slot];
                b[t] = *(const bf16x8_t*)&Bs[(ncol0 + t * 16 + m) * 64 + slot];
            }
#pragma unroll
            for (int i = 0; i < 4; i++)
#pragma unroll
                for (int j = 0; j < 4; j++)
                    acc[i][j] = __builtin_amdgcn_mfma_f32_16x16x32_bf16(a[i], b[j], acc[i][j], 0, 0, 0);
        }
        __syncthreads();
    }

#pragma unroll
    for (int i = 0; i < 4; i++) {
        const int rbase = row0 + mrow0 + i * 16 + quad * 4;
        if (outBf16) {
            us* Cb = (us*)Cv;
#pragma unroll
            for (int j = 0; j < 4; j++) {
                const int col = col0 + ncol0 + j * 16 + m;
                const float bi = bias[col];
#pragma unroll
                for (int r = 0; r < 4; r++)
                    Cb[(size_t)(rbase + r) * ldC + col] = f2b(acc[i][j][r] + bi);
            }
        } else {
            float* Cb = (float*)Cv;
#pragma unroll
            for (int j = 0; j < 4; j++) {
                const int col = col0 + ncol0 + j * 16 + m;
                const float bi = bias[col];
#pragma unroll
                for (int r = 0; r < 4; r++)
                    Cb[(size_t)(rbase + r) * ldC + col] = acc[i][j][r] + bi;
            }
        }
    }
}

// ---------------------------------------------------------------------------
// Fused projections: v (448 128x128 blocks first), then q+k (640 128x64).
// ---------------------------------------------------------------------------
__global__ __launch_bounds__(256)
void proj_kernel(const us* __restrict__ Xq, const us* __restrict__ Xk,
                 const us* __restrict__ Xv,
                 const us* __restrict__ Wqt, const us* __restrict__ Wkt,
                 const us* __restrict__ Wvt,
                 const float* __restrict__ bq, const float* __restrict__ bk,
                 const float* __restrict__ bv,
                 us* __restrict__ qbuf, us* __restrict__ kbuf,
                 us* __restrict__ vbuf)
{
    __shared__ us As[128 * 64];
    __shared__ us Bs[128 * 64];
    const int b = blockIdx.x;
    if (b < 448) {
        const int bx = b & 63, cy = b >> 6;          // 64 x 7
        gemm128_core(Xv, Wvt, bv, vbuf, D_MODEL, N_CAT, 1,
                     bx << 7, cy << 7, As, Bs);
    } else {
        const int idx = b - 448;
        const int bx = idx & 63;
        const int rest = idx >> 6;                   // 0..9
        const int cy = rest % 5, z = rest / 5;
        gemm64_core(z ? Xk : Xq, z ? Wkt : Wqt, z ? bk : bq,
                    z ? kbuf : qbuf, D_MODEL, NQK,
                    bx << 7, cy << 6, As, Bs);
    }
}

// out gemm: [8192][896] bf16 @ [896][1024] -> fp32
__global__ __launch_bounds__(256)
void gemm_out(const us* __restrict__ ab, const us* __restrict__ Wct,
              const float* __restrict__ bc, float* __restrict__ out)
{
    __shared__ us As[128 * 64];
    __shared__ us Bs[128 * 64];
    gemm128_core(ab, Wct, bc, out, N_CAT, D_MODEL, 0,
                 (int)(blockIdx.x << 7), (int)(blockIdx.y << 7), As, Bs);
}

// ---------------------------------------------------------------------------
// Attention kernel, (slab, head) decomposition: ONE head per block.
// Serial-alias staging keeps LDS small (occupancy is the lever here):
//   stage k,q -> bar -> scores->sab -> bar -> stage v (over kslab)
//   + resample+softmax->sab overwrite (overlaps v-stage) -> bar -> PV.
// sab rows are wave-private across ALL phases (p in [wave*16, wave*16+16)),
// so no barriers are needed around sab reads/writes.
// ROWS=95 (d=1, heads 0-9): LDS 31.1 KB -> 5 blocks/CU, grid (128,10).
// ROWS=312 (heads 10-13):   LDS 62.3 KB -> 2 blocks/CU, grid (128,4).
// Scores are recomputed per head (+512 VALU-inst/thread) — cheap vs the
// 5x occupancy gain over the round-4 serial-head structure.
// ---------------------------------------------------------------------------
template<int ROWS>
__global__ __launch_bounds__(256)
void attn_kernel(const us* __restrict__ qb, const us* __restrict__ kb,
                 const us* __restrict__ vb,
                 const float* __restrict__ Ws, const float* __restrict__ bs,
                 us* __restrict__ ab, int hbase)
{
    __shared__ uu    kv[ROWS * 36];     // kslab (score phase) = vslab (PV phase)
    __shared__ uu    qslab[64 * 32];
    __shared__ float sab[64 * 36];      // scores, overwritten by attn weights

    const int tid  = threadIdx.x;
    const int wave = tid >> 6;
    const int lane = tid & 63;
    const int j    = lane & 31;
    const int half = lane >> 5;
    const int h    = hbase + blockIdx.y;
    const int s    = subhead_of(h);
    const int d    = dil_of_sub(s);
    const int ml0  = blockIdx.x * 64;
    const int l0   = ml0 & 4095;
    const int bm   = ml0 - l0;
    const int W    = 64 + 31 * d;

    // ---- stage k (W x 32 uu) + q (64 x 32 uu), vectorized uu4 ----
    const uu4* kg4 = (const uu4*)kb;   // row stride 40 uu4
    const uu4* qg4 = (const uu4*)qb;   // row stride 40 uu4
    for (int idx = tid; idx < W * 8; idx += 256) {
        int r = idx >> 3, c4 = idx & 7;
        int src = l0 - 16 * d + r;
        src = src < 0 ? 0 : (src > 4095 ? 4095 : src);
        *(uu4*)&kv[r * 36 + c4 * 4] = kg4[(size_t)(bm + src) * 40 + s * 8 + c4];
    }
    for (int idx = tid; idx < 64 * 8; idx += 256) {
        int r = idx >> 3, c4 = idx & 7;
        *(uu4*)&qslab[r * 32 + c4 * 4] = qg4[(size_t)(ml0 + r) * 40 + s * 8 + c4];
    }
    __syncthreads();

    // ---- scores -> sab (rows wave-private) ----
#pragma unroll
    for (int i = 0; i < 8; i++) {
        const int p = wave * 16 + i * 2 + half;
        const uu4* k4 = (const uu4*)&kv[(p + j * d) * 36];
        const uu4* q4 = (const uu4*)&qslab[p * 32];
        float acc = 0.f;
#pragma unroll
        for (int q = 0; q < 8; q++) {
            uu4 kd = k4[q];
            uu4 qd = q4[q];
            acc = fmaf(blo(kd.x), blo(qd.x), acc); acc = fmaf(bhi(kd.x), bhi(qd.x), acc);
            acc = fmaf(blo(kd.y), blo(qd.y), acc); acc = fmaf(bhi(kd.y), bhi(qd.y), acc);
            acc = fmaf(blo(kd.z), blo(qd.z), acc); acc = fmaf(bhi(kd.z), bhi(qd.z), acc);
            acc = fmaf(blo(kd.w), blo(qd.w), acc); acc = fmaf(bhi(kd.w), bhi(qd.w), acc);
        }
        sab[p * 36 + j] = acc * 0.125f;
    }
    __syncthreads();    // all waves done reading kslab -> safe to overwrite

    // ---- stage v over kslab space (loads issued before resample VALU) ----
    const uu4* vg4 = (const uu4*)vb;   // row stride 112 uu4
    for (int idx = tid; idx < W * 8; idx += 256) {
        int r = idx >> 3, c4 = idx & 7;
        int src = l0 - 16 * d + r;
        src = src < 0 ? 0 : (src > 4095 ? 4095 : src);
        *(uu4*)&kv[r * 36 + c4 * 4] = vg4[(size_t)(bm + src) * 112 + h * 8 + c4];
    }
    float wsr[32];
#pragma unroll
    for (int k = 0; k < 32; k++) wsr[k] = Ws[(size_t)h * 1024 + k * 32 + j];
    const float bsv = bs[h * 32 + j];

    // ---- resample + softmax -> sab overwrite (wave-private rows) ----
#pragma unroll
    for (int i = 0; i < 8; i++) {
        const int p = wave * 16 + i * 2 + half;
        const float4* s4 = (const float4*)&sab[p * 36];
        float acc = bsv;
#pragma unroll
        for (int q = 0; q < 8; q++) {
            float4 v = s4[q];
            acc = fmaf(v.x, wsr[q * 4 + 0], acc);
            acc = fmaf(v.y, wsr[q * 4 + 1], acc);
            acc = fmaf(v.z, wsr[q * 4 + 2], acc);
            acc = fmaf(v.w, wsr[q * 4 + 3], acc);
        }
        float mx = acc;
#pragma unroll
        for (int off = 16; off > 0; off >>= 1) mx = fmaxf(mx, __shfl_xor(mx, off, 64));
        float ex = __expf(acc - mx);
        float sum = ex;
#pragma unroll
        for (int off = 16; off > 0; off >>= 1) sum += __shfl_xor(sum, off, 64);
        sab[p * 36 + j] = ex / sum;
    }
    __syncthreads();   // vslab fully staged

    // ---- PV: 8 positions per pass ----
    const int o = lane >> 3;     // position octet
    const int c = lane & 7;      // channel chunk (4 dwords = 8 channels)
#pragma unroll
    for (int pass = 0; pass < 2; pass++) {
        const int p  = wave * 16 + pass * 8 + o;
        const int ml = ml0 + p;
        float a0 = 0.f, a1 = 0.f, a2 = 0.f, a3 = 0.f;
        float a4 = 0.f, a5 = 0.f, a6 = 0.f, a7 = 0.f;
#pragma unroll
        for (int mm = 0; mm < 32; mm++) {
            const float at = sab[p * 36 + mm];
            uu4 vd = *(const uu4*)&kv[(p + mm * d) * 36 + c * 4];
            a0 = fmaf(blo(vd.x), at, a0); a1 = fmaf(bhi(vd.x), at, a1);
            a2 = fmaf(blo(vd.y), at, a2); a3 = fmaf(bhi(vd.y), at, a3);
            a4 = fmaf(blo(vd.z), at, a4); a5 = fmaf(bhi(vd.z), at, a5);
            a6 = fmaf(blo(vd.w), at, a6); a7 = fmaf(bhi(vd.w), at, a7);
        }
        uu4 od;
        od.x = pack2(a0, a1); od.y = pack2(a2, a3);
        od.z = pack2(a4, a5); od.w = pack2(a6, a7);
        *(uu4*)&((uu*)ab)[(size_t)ml * 448 + h * 32 + c * 4] = od;
    }
}

// ---------------------------------------------------------------------------
extern "C" void kernel_launch(void* const* d_in, const int* in_sizes, int n_in,
                              void* d_out, int out_size, void* d_ws, size_t ws_size,
                              hipStream_t stream)
{
    const float* query = (const float*)d_in[0];
    const float* key   = (const float*)d_in[1];
    const float* value = (const float*)d_in[2];
    const float* Wq    = (const float*)d_in[3];
    const float* bq    = (const float*)d_in[4];
    const float* Wk    = (const float*)d_in[5];
    const float* bk    = (const float*)d_in[6];
    const float* Wv    = (const float*)d_in[7];
    const float* bv    = (const float*)d_in[8];
    const float* Ws    = (const float*)d_in[9];
    const float* bs    = (const float*)d_in[10];
    const float* Wc    = (const float*)d_in[11];
    const float* bc    = (const float*)d_in[12];
    float* out = (float*)d_out;

    // workspace carve (bf16 elements). ab aliases Xq (Xq dead after q gemm).
    us* w = (us*)d_ws;
    us* Xq  = w;                          // 8192*1024
    us* ab  = w;                          // 8192*896 (alias of Xq)
    us* Xk  = Xq  + (size_t)M_ROWS * D_MODEL;
    us* Xv  = Xk  + (size_t)M_ROWS * D_MODEL;
    us* Wqt = Xv  + (size_t)M_ROWS * D_MODEL;           // [320][1024]
    us* Wkt = Wqt + (size_t)SUBHEADS * D_INT * D_MODEL;
    us* Wvt = Wkt + (size_t)SUBHEADS * D_INT * D_MODEL; // [896][1024]
    us* Wct = Wvt + (size_t)HEADS * D_INT * D_MODEL;    // [1024][896]
    us* qbuf = Wct + (size_t)D_MODEL * N_CAT;           // [8192][320]
    us* kbuf = qbuf + (size_t)M_ROWS * NQK;
    us* vbuf = kbuf + (size_t)M_ROWS * NQK;             // [8192][896]

    dim3 blk(256);

    // prep: grid-stride q/k/v casts + weight transposes in one launch
    prep_kernel<<<dim3(CAST_BLK + 2432), blk, 0, stream>>>(
        (const float4*)query, (const float4*)key, (const float4*)value,
        Wq, Wk, Wv, Wc, Xq, Xk, Xv, Wqt, Wkt, Wvt, Wct);

    // fused q/k/v projections (bf16 A via global_load_lds): 1088 blocks
    proj_kernel<<<dim3(1088), blk, 0, stream>>>(
        Xq, Xk, Xv, Wqt, Wkt, Wvt, bq, bk, bv, qbuf, kbuf, vbuf);

    // attention, one head per block:
    //   heads 0-9 (d=1, W=95):   grid 1280, LDS 31.1 KB -> 5 blocks/CU
    //   heads 10-13 (W<=312):    grid 512,  LDS 62.3 KB -> 2 blocks/CU
    attn_kernel<95><<<dim3(M_ROWS / 64, 10), blk, 0, stream>>>(
        qbuf, kbuf, vbuf, Ws, bs, ab, 0);
    attn_kernel<312><<<dim3(M_ROWS / 64, 4), blk, 0, stream>>>(
        qbuf, kbuf, vbuf, Ws, bs, ab, 10);

    // out gemm: [8192][896] @ [896][1024] -> fp32 (128x128 tile)
    gemm_out<<<dim3(M_ROWS / 128, D_MODEL / 128), blk, 0, stream>>>(
        ab, Wct, bc, out);
}

// Round 6
// 279.913 us; speedup vs baseline: 1.0870x; 1.0164x over previous
//
#include <hip/hip_runtime.h>
#include <math.h>

#define D_MODEL 1024
#define D_INT   64
#define KW      32
#define L_SEQ   4096
#define SUBHEADS 5
#define HEADS   14
#define M_ROWS  8192
#define N_CAT   896
#define NQK     320          // SUBHEADS*64

typedef unsigned short us;
typedef unsigned int   uu;
typedef __attribute__((ext_vector_type(4))) unsigned int uu4;
typedef __attribute__((ext_vector_type(8))) short bf16x8_t;
typedef __attribute__((ext_vector_type(4))) float f32x4_t;

__device__ __forceinline__ float u2f(uu u) {
    float f; __builtin_memcpy(&f, &u, 4); return f;
}
__device__ __forceinline__ float blo(uu u) { return u2f(u << 16); }
__device__ __forceinline__ float bhi(uu u) { return u2f(u & 0xffff0000u); }
__device__ __forceinline__ us f2b(float f) {
    uu u; __builtin_memcpy(&u, &f, 4);
    u += 0x7fffu + ((u >> 16) & 1u);
    return (us)(u >> 16);
}
__device__ __forceinline__ uu pack2(float a, float b) {
    return (uu)f2b(a) | ((uu)f2b(b) << 16);
}
// hardware packed cvt: RNE, bit-identical to pack2
__device__ __forceinline__ uu cvtpk(float a, float b) {
    uu r;
    asm("v_cvt_pk_bf16_f32 %0, %1, %2" : "=v"(r) : "v"(a), "v"(b));
    return r;
}
__device__ __forceinline__ void load16(void* lds, const void* g) {
    __builtin_amdgcn_global_load_lds(
        (const __attribute__((address_space(1))) unsigned int*)g,
        (__attribute__((address_space(3))) unsigned int*)lds, 16, 0, 0);
}
__device__ __forceinline__ int subhead_of(int h) {
    return (h < 5) ? 0 : (h < 10) ? 1 : (h < 12) ? 2 : (h == 12) ? 3 : 4;
}

// ---------------------------------------------------------------------------
// Prep mega-kernel: grid-stride q/k/v casts (blocks [0,1536)) + 32x32 weight
// transpose-casts (blocks [1536,3968)).
// ---------------------------------------------------------------------------
#define CAST_BLK 1536
__global__ __launch_bounds__(256)
void prep_kernel(const float4* __restrict__ q, const float4* __restrict__ k,
                 const float4* __restrict__ v,
                 const float* __restrict__ Wq, const float* __restrict__ Wk,
                 const float* __restrict__ Wv, const float* __restrict__ Wc,
                 us* __restrict__ Xq, us* __restrict__ Xk, us* __restrict__ Xv,
                 us* __restrict__ Wqt, us* __restrict__ Wkt,
                 us* __restrict__ Wvt, us* __restrict__ Wct)
{
    __shared__ float t[32][33];
    const int tid = threadIdx.x;
    const int b = blockIdx.x;

    if (b < CAST_BLK) {
        const int arr = b >> 9;               // 0,1,2
        const int blk = b & 511;
        const float4* s = (arr == 0) ? q : (arr == 1) ? k : v;
        uu4* d = (uu4*)((arr == 0) ? Xq : (arr == 1) ? Xk : Xv);
        const int tg = blk * 256 + tid;       // 0..131071
#pragma unroll
        for (int it = 0; it < 8; it++) {
            const int i = tg + it * 131072;
            float4 x0 = s[2 * i];
            float4 x1 = s[2 * i + 1];
            uu4 o;
            o.x = cvtpk(x0.x, x0.y); o.y = cvtpk(x0.z, x0.w);
            o.z = cvtpk(x1.x, x1.y); o.w = cvtpk(x1.z, x1.w);
            d[i] = o;
        }
        return;
    }

    int g = b - CAST_BLK;
    const float* S; us* D; int K, N;
    if (g < 640) {
        if (g < 320) { S = Wq; D = Wqt; } else { S = Wk; D = Wkt; g -= 320; }
        K = 1024; N = 64;
    } else if (g < 1536) {
        g -= 640; S = Wv; D = Wvt; K = 1024; N = 64;
    } else {
        g -= 1536; S = Wc; D = Wct; K = 896; N = 1024;
    }
    const int nkx = K >> 5;
    const int kx = g % nkx;
    const int rest = g / nkx;
    const int ny = rest % (N >> 5);
    const int z  = rest / (N >> 5);
    const int k0 = kx * 32, n0 = ny * 32;
    S += (size_t)z * K * N;
    D += (size_t)z * K * N;
    const int tx = tid & 31, ty = tid >> 5;
#pragma unroll
    for (int r = 0; r < 32; r += 8)
        t[r + ty][tx] = S[(size_t)(k0 + r + ty) * N + n0 + tx];
    __syncthreads();
#pragma unroll
    for (int r = 0; r < 32; r += 8)
        D[(size_t)(n0 + r + ty) * K + k0 + tx] = f2b(t[tx][r + ty]);
}

// ---------------------------------------------------------------------------
// 128x64-tile GEMM core (BK=64, XOR-swizzled LDS, global_load_lds 16B)
// ---------------------------------------------------------------------------
__device__ __forceinline__
void gemm64_core(const us* __restrict__ A, const us* __restrict__ Bt,
                 const float* __restrict__ bias, us* __restrict__ C,
                 int K, int ldC, int row0, int col0, us* As, us* Bs)
{
    const int tid = threadIdx.x, w = tid >> 6, lane = tid & 63;
    const int m = lane & 15, quad = lane >> 4;
    const int sr = lane >> 3;
    const int scs = (lane & 7) ^ sr;

    f32x4_t z4 = {0.f, 0.f, 0.f, 0.f};
    f32x4_t acc[2][4] = {{z4, z4, z4, z4}, {z4, z4, z4, z4}};

    for (int k0 = 0; k0 < K; k0 += 64) {
#pragma unroll
        for (int p = 0; p < 4; p++) {
            const int r = w * 32 + p * 8 + sr;
            load16(&As[(w * 32 + p * 8) * 64], A + (size_t)(row0 + r) * K + k0 + scs * 8);
        }
#pragma unroll
        for (int p = 0; p < 2; p++) {
            const int r = w * 16 + p * 8 + sr;
            load16(&Bs[(w * 16 + p * 8) * 64], Bt + (size_t)(col0 + r) * K + k0 + scs * 8);
        }
        __syncthreads();
#pragma unroll
        for (int ks = 0; ks < 2; ks++) {
            const int slot = ((ks * 4 + quad) ^ (m & 7)) * 8;
            bf16x8_t a0 = *(const bf16x8_t*)&As[(w * 32 + m) * 64 + slot];
            bf16x8_t a1 = *(const bf16x8_t*)&As[(w * 32 + 16 + m) * 64 + slot];
#pragma unroll
            for (int t = 0; t < 4; t++) {
                bf16x8_t bb = *(const bf16x8_t*)&Bs[(t * 16 + m) * 64 + slot];
                acc[0][t] = __builtin_amdgcn_mfma_f32_16x16x32_bf16(a0, bb, acc[0][t], 0, 0, 0);
                acc[1][t] = __builtin_amdgcn_mfma_f32_16x16x32_bf16(a1, bb, acc[1][t], 0, 0, 0);
            }
        }
        __syncthreads();
    }

#pragma unroll
    for (int tm = 0; tm < 2; tm++) {
        const int rbase = row0 + w * 32 + tm * 16 + quad * 4;
#pragma unroll
        for (int t = 0; t < 4; t++) {
            const int col = col0 + t * 16 + m;
            const float bi = bias[col];
#pragma unroll
            for (int r = 0; r < 4; r++)
                C[(size_t)(rbase + r) * ldC + col] = f2b(acc[tm][t][r] + bi);
        }
    }
}

// ---------------------------------------------------------------------------
// 128x128-tile core (m97 structure)
// ---------------------------------------------------------------------------
__device__ __forceinline__
void gemm128_core(const us* __restrict__ A, const us* __restrict__ Bt,
                  const float* __restrict__ bias, void* __restrict__ Cv,
                  int K, int ldC, int outBf16, int row0, int col0,
                  us* As, us* Bs)
{
    const int tid = threadIdx.x, w = tid >> 6, lane = tid & 63;
    const int m = lane & 15, quad = lane >> 4;
    const int sr = lane >> 3;
    const int scs = (lane & 7) ^ sr;
    const int mrow0 = (w & 1) * 64, ncol0 = (w >> 1) * 64;

    f32x4_t z = {0.f, 0.f, 0.f, 0.f};
    f32x4_t acc[4][4] = {{z,z,z,z},{z,z,z,z},{z,z,z,z},{z,z,z,z}};

    for (int k0 = 0; k0 < K; k0 += 64) {
#pragma unroll
        for (int p = 0; p < 4; p++) {
            const int r = w * 32 + p * 8 + sr;
            load16(&As[(w * 32 + p * 8) * 64], A  + (size_t)(row0 + r) * K + k0 + scs * 8);
            load16(&Bs[(w * 32 + p * 8) * 64], Bt + (size_t)(col0 + r) * K + k0 + scs * 8);
        }
        __syncthreads();
#pragma unroll
        for (int ks = 0; ks < 2; ks++) {
            const int slot = ((ks * 4 + quad) ^ (m & 7)) * 8;
            bf16x8_t a[4], b[4];
#pragma unroll
            for (int t = 0; t < 4; t++) {
                a[t] = *(const bf16x8_t*)&As[(mrow0 + t * 16 + m) * 64 + slot];
                b[t] = *(const bf16x8_t*)&Bs[(ncol0 + t * 16 + m) * 64 + slot];
            }
#pragma unroll
            for (int i = 0; i < 4; i++)
#pragma unroll
                for (int j = 0; j < 4; j++)
                    acc[i][j] = __builtin_amdgcn_mfma_f32_16x16x32_bf16(a[i], b[j], acc[i][j], 0, 0, 0);
        }
        __syncthreads();
    }

#pragma unroll
    for (int i = 0; i < 4; i++) {
        const int rbase = row0 + mrow0 + i * 16 + quad * 4;
        if (outBf16) {
            us* Cb = (us*)Cv;
#pragma unroll
            for (int j = 0; j < 4; j++) {
                const int col = col0 + ncol0 + j * 16 + m;
                const float bi = bias[col];
#pragma unroll
                for (int r = 0; r < 4; r++)
                    Cb[(size_t)(rbase + r) * ldC + col] = f2b(acc[i][j][r] + bi);
            }
        } else {
            float* Cb = (float*)Cv;
#pragma unroll
            for (int j = 0; j < 4; j++) {
                const int col = col0 + ncol0 + j * 16 + m;
                const float bi = bias[col];
#pragma unroll
                for (int r = 0; r < 4; r++)
                    Cb[(size_t)(rbase + r) * ldC + col] = acc[i][j][r] + bi;
            }
        }
    }
}

// ---------------------------------------------------------------------------
// Fused projections: v (448 128x128 blocks first), then q+k (640 128x64).
// ---------------------------------------------------------------------------
__global__ __launch_bounds__(256)
void proj_kernel(const us* __restrict__ Xq, const us* __restrict__ Xk,
                 const us* __restrict__ Xv,
                 const us* __restrict__ Wqt, const us* __restrict__ Wkt,
                 const us* __restrict__ Wvt,
                 const float* __restrict__ bq, const float* __restrict__ bk,
                 const float* __restrict__ bv,
                 us* __restrict__ qbuf, us* __restrict__ kbuf,
                 us* __restrict__ vbuf)
{
    __shared__ us As[128 * 64];
    __shared__ us Bs[128 * 64];
    const int b = blockIdx.x;
    if (b < 448) {
        const int bx = b & 63, cy = b >> 6;          // 64 x 7
        gemm128_core(Xv, Wvt, bv, vbuf, D_MODEL, N_CAT, 1,
                     bx << 7, cy << 7, As, Bs);
    } else {
        const int idx = b - 448;
        const int bx = idx & 63;
        const int rest = idx >> 6;                   // 0..9
        const int cy = rest % 5, z = rest / 5;
        gemm64_core(z ? Xk : Xq, z ? Wkt : Wqt, z ? bk : bq,
                    z ? kbuf : qbuf, D_MODEL, NQK,
                    bx << 7, cy << 6, As, Bs);
    }
}

// out gemm: [8192][896] bf16 @ [896][1024] -> fp32
__global__ __launch_bounds__(256)
void gemm_out(const us* __restrict__ ab, const us* __restrict__ Wct,
              const float* __restrict__ bc, float* __restrict__ out)
{
    __shared__ us As[128 * 64];
    __shared__ us Bs[128 * 64];
    gemm128_core(ab, Wct, bc, out, N_CAT, D_MODEL, 0,
                 (int)(blockIdx.x << 7), (int)(blockIdx.y << 7), As, Bs);
}

// ---------------------------------------------------------------------------
// Attention kernel, (slab, head) decomposition, sigma-interleaved kv layout.
//
// kv row r (local window row) is stored at LDS slot
//      sigma(r) = (r mod d)*(W/d) + (r >> log2 d)          [bijective: d | W]
// so rows {p + j*d} map to CONSECUTIVE slots (stride-36-dword rows ->
// distinct bank-quads) — conflict-free score & PV reads for ALL d.
// For d=1 sigma is identity (layout unchanged from the proven kernel).
//
// q staged via global_load_lds (qslab is linear [64][32] dwords).
// PV reads attention weights batched (2x float4 per 8-mm group).
// sab rows wave-private through all phases; 3 barriers per block.
// ---------------------------------------------------------------------------
template<int ROWS>
__global__ __launch_bounds__(256)
void attn_kernel(const us* __restrict__ qb, const us* __restrict__ kb,
                 const us* __restrict__ vb,
                 const float* __restrict__ Ws, const float* __restrict__ bs,
                 us* __restrict__ ab, int hbase)
{
    __shared__ uu    kv[ROWS * 36];     // kslab (score phase) = vslab (PV phase)
    __shared__ uu    qslab[64 * 32];
    __shared__ float sab[64 * 36];      // scores, overwritten by attn weights

    const int tid  = threadIdx.x;
    const int wave = tid >> 6;
    const int lane = tid & 63;
    const int j    = lane & 31;
    const int half = lane >> 5;
    const int h    = hbase + blockIdx.y;
    const int s    = subhead_of(h);
    const int ld   = (s <= 1) ? 0 : (s - 1);     // log2(dilation)
    const int d    = 1 << ld;
    const int ml0  = blockIdx.x * 64;
    const int l0   = ml0 & 4095;
    const int bm   = ml0 - l0;
    const int W    = 64 + 31 * d;
    const int Bseg = W >> ld;                    // W/d (exact)

    // ---- stage k (sigma layout) + q (gload_lds, linear) ----
    const uu4* kg4 = (const uu4*)kb;   // row stride 40 uu4
    const uu4* qg4 = (const uu4*)qb;   // row stride 40 uu4
    for (int idx = tid; idx < W * 8; idx += 256) {
        int r = idx >> 3, c4 = idx & 7;
        int src = l0 - 16 * d + r;
        src = src < 0 ? 0 : (src > 4095 ? 4095 : src);
        int slot = (r & (d - 1)) * Bseg + (r >> ld);
        *(uu4*)&kv[slot * 36 + c4 * 4] = kg4[(size_t)(bm + src) * 40 + s * 8 + c4];
    }
#pragma unroll
    for (int it = 0; it < 2; it++) {
        const int idx = it * 256 + tid;
        const int r = idx >> 3, c4 = idx & 7;
        load16(&qslab[(it * 256 + wave * 64) * 4],
               &qg4[(size_t)(ml0 + r) * 40 + s * 8 + c4]);
    }
    __syncthreads();

    // ---- scores -> sab (rows wave-private) ----
#pragma unroll
    for (int i = 0; i < 8; i++) {
        const int p = wave * 16 + i * 2 + half;
        const int sb = (p & (d - 1)) * Bseg + (p >> ld);
        const uu4* k4 = (const uu4*)&kv[(sb + j) * 36];
        const uu4* q4 = (const uu4*)&qslab[p * 32];
        float acc = 0.f;
#pragma unroll
        for (int q = 0; q < 8; q++) {
            uu4 kd = k4[q];
            uu4 qd = q4[q];
            acc = fmaf(blo(kd.x), blo(qd.x), acc); acc = fmaf(bhi(kd.x), bhi(qd.x), acc);
            acc = fmaf(blo(kd.y), blo(qd.y), acc); acc = fmaf(bhi(kd.y), bhi(qd.y), acc);
            acc = fmaf(blo(kd.z), blo(qd.z), acc); acc = fmaf(bhi(kd.z), bhi(qd.z), acc);
            acc = fmaf(blo(kd.w), blo(qd.w), acc); acc = fmaf(bhi(kd.w), bhi(qd.w), acc);
        }
        sab[p * 36 + j] = acc * 0.125f;
    }
    __syncthreads();    // all waves done reading kslab -> safe to overwrite

    // ---- stage v over kslab space (sigma layout; issued before resample) ----
    const uu4* vg4 = (const uu4*)vb;   // row stride 112 uu4
    for (int idx = tid; idx < W * 8; idx += 256) {
        int r = idx >> 3, c4 = idx & 7;
        int src = l0 - 16 * d + r;
        src = src < 0 ? 0 : (src > 4095 ? 4095 : src);
        int slot = (r & (d - 1)) * Bseg + (r >> ld);
        *(uu4*)&kv[slot * 36 + c4 * 4] = vg4[(size_t)(bm + src) * 112 + h * 8 + c4];
    }
    float wsr[32];
#pragma unroll
    for (int k = 0; k < 32; k++) wsr[k] = Ws[(size_t)h * 1024 + k * 32 + j];
    const float bsv = bs[h * 32 + j];

    // ---- resample + softmax -> sab overwrite (wave-private rows) ----
#pragma unroll
    for (int i = 0; i < 8; i++) {
        const int p = wave * 16 + i * 2 + half;
        const float4* s4 = (const float4*)&sab[p * 36];
        float acc = bsv;
#pragma unroll
        for (int q = 0; q < 8; q++) {
            float4 v = s4[q];
            acc = fmaf(v.x, wsr[q * 4 + 0], acc);
            acc = fmaf(v.y, wsr[q * 4 + 1], acc);
            acc = fmaf(v.z, wsr[q * 4 + 2], acc);
            acc = fmaf(v.w, wsr[q * 4 + 3], acc);
        }
        float mx = acc;
#pragma unroll
        for (int off = 16; off > 0; off >>= 1) mx = fmaxf(mx, __shfl_xor(mx, off, 64));
        float ex = __expf(acc - mx);
        float sum = ex;
#pragma unroll
        for (int off = 16; off > 0; off >>= 1) sum += __shfl_xor(sum, off, 64);
        sab[p * 36 + j] = ex / sum;
    }
    __syncthreads();   // vslab fully staged

    // ---- PV: 8 positions per pass, at-weights batched 8-at-a-time ----
    const int o = lane >> 3;     // position octet
    const int c = lane & 7;      // channel chunk (4 dwords = 8 channels)
#pragma unroll
    for (int pass = 0; pass < 2; pass++) {
        const int p  = wave * 16 + pass * 8 + o;
        const int ml = ml0 + p;
        const int sbp = (p & (d - 1)) * Bseg + (p >> ld);
        float a0 = 0.f, a1 = 0.f, a2 = 0.f, a3 = 0.f;
        float a4 = 0.f, a5 = 0.f, a6 = 0.f, a7 = 0.f;
#pragma unroll
        for (int mg = 0; mg < 4; mg++) {
            const float4 wA = *(const float4*)&sab[p * 36 + mg * 8];
            const float4 wB = *(const float4*)&sab[p * 36 + mg * 8 + 4];
            const float at8[8] = {wA.x, wA.y, wA.z, wA.w, wB.x, wB.y, wB.z, wB.w};
#pragma unroll
            for (int m2 = 0; m2 < 8; m2++) {
                const float at = at8[m2];
                uu4 vd = *(const uu4*)&kv[(sbp + mg * 8 + m2) * 36 + c * 4];
                a0 = fmaf(blo(vd.x), at, a0); a1 = fmaf(bhi(vd.x), at, a1);
                a2 = fmaf(blo(vd.y), at, a2); a3 = fmaf(bhi(vd.y), at, a3);
                a4 = fmaf(blo(vd.z), at, a4); a5 = fmaf(bhi(vd.z), at, a5);
                a6 = fmaf(blo(vd.w), at, a6); a7 = fmaf(bhi(vd.w), at, a7);
            }
        }
        uu4 od;
        od.x = pack2(a0, a1); od.y = pack2(a2, a3);
        od.z = pack2(a4, a5); od.w = pack2(a6, a7);
        *(uu4*)&((uu*)ab)[(size_t)ml * 448 + h * 32 + c * 4] = od;
    }
}

// ---------------------------------------------------------------------------
extern "C" void kernel_launch(void* const* d_in, const int* in_sizes, int n_in,
                              void* d_out, int out_size, void* d_ws, size_t ws_size,
                              hipStream_t stream)
{
    const float* query = (const float*)d_in[0];
    const float* key   = (const float*)d_in[1];
    const float* value = (const float*)d_in[2];
    const float* Wq    = (const float*)d_in[3];
    const float* bq    = (const float*)d_in[4];
    const float* Wk    = (const float*)d_in[5];
    const float* bk    = (const float*)d_in[6];
    const float* Wv    = (const float*)d_in[7];
    const float* bv    = (const float*)d_in[8];
    const float* Ws    = (const float*)d_in[9];
    const float* bs    = (const float*)d_in[10];
    const float* Wc    = (const float*)d_in[11];
    const float* bc    = (const float*)d_in[12];
    float* out = (float*)d_out;

    // workspace carve (bf16 elements). ab aliases Xq (Xq dead after q gemm).
    us* w = (us*)d_ws;
    us* Xq  = w;                          // 8192*1024
    us* ab  = w;                          // 8192*896 (alias of Xq)
    us* Xk  = Xq  + (size_t)M_ROWS * D_MODEL;
    us* Xv  = Xk  + (size_t)M_ROWS * D_MODEL;
    us* Wqt = Xv  + (size_t)M_ROWS * D_MODEL;           // [320][1024]
    us* Wkt = Wqt + (size_t)SUBHEADS * D_INT * D_MODEL;
    us* Wvt = Wkt + (size_t)SUBHEADS * D_INT * D_MODEL; // [896][1024]
    us* Wct = Wvt + (size_t)HEADS * D_INT * D_MODEL;    // [1024][896]
    us* qbuf = Wct + (size_t)D_MODEL * N_CAT;           // [8192][320]
    us* kbuf = qbuf + (size_t)M_ROWS * NQK;
    us* vbuf = kbuf + (size_t)M_ROWS * NQK;             // [8192][896]

    dim3 blk(256);

    // prep: grid-stride q/k/v casts + weight transposes in one launch
    prep_kernel<<<dim3(CAST_BLK + 2432), blk, 0, stream>>>(
        (const float4*)query, (const float4*)key, (const float4*)value,
        Wq, Wk, Wv, Wc, Xq, Xk, Xv, Wqt, Wkt, Wvt, Wct);

    // fused q/k/v projections (bf16 A via global_load_lds): 1088 blocks
    proj_kernel<<<dim3(1088), blk, 0, stream>>>(
        Xq, Xk, Xv, Wqt, Wkt, Wvt, bq, bk, bv, qbuf, kbuf, vbuf);

    // attention, one head per block:
    //   heads 0-9 (d=1, W=95):   grid 1280, LDS 31.1 KB -> 5 blocks/CU
    //   heads 10-13 (W<=312):    grid 512,  LDS 62.3 KB -> 2 blocks/CU
    attn_kernel<95><<<dim3(M_ROWS / 64, 10), blk, 0, stream>>>(
        qbuf, kbuf, vbuf, Ws, bs, ab, 0);
    attn_kernel<312><<<dim3(M_ROWS / 64, 4), blk, 0, stream>>>(
        qbuf, kbuf, vbuf, Ws, bs, ab, 10);

    // out gemm: [8192][896] @ [896][1024] -> fp32 (128x128 tile)
    gemm_out<<<dim3(M_ROWS / 128, D_MODEL / 128), blk, 0, stream>>>(
        ab, Wct, bc, out);
}

// Round 7
// 278.061 us; speedup vs baseline: 1.0943x; 1.0067x over previous
//
#include <hip/hip_runtime.h>
#include <math.h>

#define D_MODEL 1024
#define D_INT   64
#define KW      32
#define L_SEQ   4096
#define SUBHEADS 5
#define HEADS   14
#define M_ROWS  8192
#define N_CAT   896
#define NQK     320          // SUBHEADS*64

typedef unsigned short us;
typedef unsigned int   uu;
typedef __attribute__((ext_vector_type(4))) unsigned int uu4;
typedef __attribute__((ext_vector_type(8))) short bf16x8_t;
typedef __attribute__((ext_vector_type(4))) float f32x4_t;

__device__ __forceinline__ float u2f(uu u) {
    float f; __builtin_memcpy(&f, &u, 4); return f;
}
__device__ __forceinline__ float blo(uu u) { return u2f(u << 16); }
__device__ __forceinline__ float bhi(uu u) { return u2f(u & 0xffff0000u); }
__device__ __forceinline__ us f2b(float f) {
    uu u; __builtin_memcpy(&u, &f, 4);
    u += 0x7fffu + ((u >> 16) & 1u);
    return (us)(u >> 16);
}
__device__ __forceinline__ uu pack2(float a, float b) {
    return (uu)f2b(a) | ((uu)f2b(b) << 16);
}
// hardware packed cvt: RNE, bit-identical to pack2
__device__ __forceinline__ uu cvtpk(float a, float b) {
    uu r;
    asm("v_cvt_pk_bf16_f32 %0, %1, %2" : "=v"(r) : "v"(a), "v"(b));
    return r;
}
__device__ __forceinline__ void load16(void* lds, const void* g) {
    __builtin_amdgcn_global_load_lds(
        (const __attribute__((address_space(1))) unsigned int*)g,
        (__attribute__((address_space(3))) unsigned int*)lds, 16, 0, 0);
}
__device__ __forceinline__ int subhead_of(int h) {
    return (h < 5) ? 0 : (h < 10) ? 1 : (h < 12) ? 2 : (h == 12) ? 3 : 4;
}

// ---------------------------------------------------------------------------
// Prep mega-kernel: grid-stride q/k/v casts (blocks [0,1536)) + 32x32 weight
// transpose-casts (blocks [1536,3968)).
// ---------------------------------------------------------------------------
#define CAST_BLK 1536
__global__ __launch_bounds__(256)
void prep_kernel(const float4* __restrict__ q, const float4* __restrict__ k,
                 const float4* __restrict__ v,
                 const float* __restrict__ Wq, const float* __restrict__ Wk,
                 const float* __restrict__ Wv, const float* __restrict__ Wc,
                 us* __restrict__ Xq, us* __restrict__ Xk, us* __restrict__ Xv,
                 us* __restrict__ Wqt, us* __restrict__ Wkt,
                 us* __restrict__ Wvt, us* __restrict__ Wct)
{
    __shared__ float t[32][33];
    const int tid = threadIdx.x;
    const int b = blockIdx.x;

    if (b < CAST_BLK) {
        const int arr = b >> 9;               // 0,1,2
        const int blk = b & 511;
        const float4* s = (arr == 0) ? q : (arr == 1) ? k : v;
        uu4* d = (uu4*)((arr == 0) ? Xq : (arr == 1) ? Xk : Xv);
        const int tg = blk * 256 + tid;       // 0..131071
#pragma unroll
        for (int it = 0; it < 8; it++) {
            const int i = tg + it * 131072;
            float4 x0 = s[2 * i];
            float4 x1 = s[2 * i + 1];
            uu4 o;
            o.x = cvtpk(x0.x, x0.y); o.y = cvtpk(x0.z, x0.w);
            o.z = cvtpk(x1.x, x1.y); o.w = cvtpk(x1.z, x1.w);
            d[i] = o;
        }
        return;
    }

    int g = b - CAST_BLK;
    const float* S; us* D; int K, N;
    if (g < 640) {
        if (g < 320) { S = Wq; D = Wqt; } else { S = Wk; D = Wkt; g -= 320; }
        K = 1024; N = 64;
    } else if (g < 1536) {
        g -= 640; S = Wv; D = Wvt; K = 1024; N = 64;
    } else {
        g -= 1536; S = Wc; D = Wct; K = 896; N = 1024;
    }
    const int nkx = K >> 5;
    const int kx = g % nkx;
    const int rest = g / nkx;
    const int ny = rest % (N >> 5);
    const int z  = rest / (N >> 5);
    const int k0 = kx * 32, n0 = ny * 32;
    S += (size_t)z * K * N;
    D += (size_t)z * K * N;
    const int tx = tid & 31, ty = tid >> 5;
#pragma unroll
    for (int r = 0; r < 32; r += 8)
        t[r + ty][tx] = S[(size_t)(k0 + r + ty) * N + n0 + tx];
    __syncthreads();
#pragma unroll
    for (int r = 0; r < 32; r += 8)
        D[(size_t)(n0 + r + ty) * K + k0 + tx] = f2b(t[tx][r + ty]);
}

// ---------------------------------------------------------------------------
// 128x64-tile GEMM core (BK=64, XOR-swizzled LDS, global_load_lds 16B)
// kept only for the q/k 64-col remainder (cols 256-319).
// ---------------------------------------------------------------------------
__device__ __forceinline__
void gemm64_core(const us* __restrict__ A, const us* __restrict__ Bt,
                 const float* __restrict__ bias, us* __restrict__ C,
                 int K, int ldC, int row0, int col0, us* As, us* Bs)
{
    const int tid = threadIdx.x, w = tid >> 6, lane = tid & 63;
    const int m = lane & 15, quad = lane >> 4;
    const int sr = lane >> 3;
    const int scs = (lane & 7) ^ sr;

    f32x4_t z4 = {0.f, 0.f, 0.f, 0.f};
    f32x4_t acc[2][4] = {{z4, z4, z4, z4}, {z4, z4, z4, z4}};

    for (int k0 = 0; k0 < K; k0 += 64) {
#pragma unroll
        for (int p = 0; p < 4; p++) {
            const int r = w * 32 + p * 8 + sr;
            load16(&As[(w * 32 + p * 8) * 64], A + (size_t)(row0 + r) * K + k0 + scs * 8);
        }
#pragma unroll
        for (int p = 0; p < 2; p++) {
            const int r = w * 16 + p * 8 + sr;
            load16(&Bs[(w * 16 + p * 8) * 64], Bt + (size_t)(col0 + r) * K + k0 + scs * 8);
        }
        __syncthreads();
#pragma unroll
        for (int ks = 0; ks < 2; ks++) {
            const int slot = ((ks * 4 + quad) ^ (m & 7)) * 8;
            bf16x8_t a0 = *(const bf16x8_t*)&As[(w * 32 + m) * 64 + slot];
            bf16x8_t a1 = *(const bf16x8_t*)&As[(w * 32 + 16 + m) * 64 + slot];
#pragma unroll
            for (int t = 0; t < 4; t++) {
                bf16x8_t bb = *(const bf16x8_t*)&Bs[(t * 16 + m) * 64 + slot];
                acc[0][t] = __builtin_amdgcn_mfma_f32_16x16x32_bf16(a0, bb, acc[0][t], 0, 0, 0);
                acc[1][t] = __builtin_amdgcn_mfma_f32_16x16x32_bf16(a1, bb, acc[1][t], 0, 0, 0);
            }
        }
        __syncthreads();
    }

#pragma unroll
    for (int tm = 0; tm < 2; tm++) {
        const int rbase = row0 + w * 32 + tm * 16 + quad * 4;
#pragma unroll
        for (int t = 0; t < 4; t++) {
            const int col = col0 + t * 16 + m;
            const float bi = bias[col];
#pragma unroll
            for (int r = 0; r < 4; r++)
                C[(size_t)(rbase + r) * ldC + col] = f2b(acc[tm][t][r] + bi);
        }
    }
}

// ---------------------------------------------------------------------------
// 128x128-tile core (m97 structure)
// ---------------------------------------------------------------------------
__device__ __forceinline__
void gemm128_core(const us* __restrict__ A, const us* __restrict__ Bt,
                  const float* __restrict__ bias, void* __restrict__ Cv,
                  int K, int ldC, int outBf16, int row0, int col0,
                  us* As, us* Bs)
{
    const int tid = threadIdx.x, w = tid >> 6, lane = tid & 63;
    const int m = lane & 15, quad = lane >> 4;
    const int sr = lane >> 3;
    const int scs = (lane & 7) ^ sr;
    const int mrow0 = (w & 1) * 64, ncol0 = (w >> 1) * 64;

    f32x4_t z = {0.f, 0.f, 0.f, 0.f};
    f32x4_t acc[4][4] = {{z,z,z,z},{z,z,z,z},{z,z,z,z},{z,z,z,z}};

    for (int k0 = 0; k0 < K; k0 += 64) {
#pragma unroll
        for (int p = 0; p < 4; p++) {
            const int r = w * 32 + p * 8 + sr;
            load16(&As[(w * 32 + p * 8) * 64], A  + (size_t)(row0 + r) * K + k0 + scs * 8);
            load16(&Bs[(w * 32 + p * 8) * 64], Bt + (size_t)(col0 + r) * K + k0 + scs * 8);
        }
        __syncthreads();
#pragma unroll
        for (int ks = 0; ks < 2; ks++) {
            const int slot = ((ks * 4 + quad) ^ (m & 7)) * 8;
            bf16x8_t a[4], b[4];
#pragma unroll
            for (int t = 0; t < 4; t++) {
                a[t] = *(const bf16x8_t*)&As[(mrow0 + t * 16 + m) * 64 + slot];
                b[t] = *(const bf16x8_t*)&Bs[(ncol0 + t * 16 + m) * 64 + slot];
            }
#pragma unroll
            for (int i = 0; i < 4; i++)
#pragma unroll
                for (int j = 0; j < 4; j++)
                    acc[i][j] = __builtin_amdgcn_mfma_f32_16x16x32_bf16(a[i], b[j], acc[i][j], 0, 0, 0);
        }
        __syncthreads();
    }

#pragma unroll
    for (int i = 0; i < 4; i++) {
        const int rbase = row0 + mrow0 + i * 16 + quad * 4;
        if (outBf16) {
            us* Cb = (us*)Cv;
#pragma unroll
            for (int j = 0; j < 4; j++) {
                const int col = col0 + ncol0 + j * 16 + m;
                const float bi = bias[col];
#pragma unroll
                for (int r = 0; r < 4; r++)
                    Cb[(size_t)(rbase + r) * ldC + col] = f2b(acc[i][j][r] + bi);
            }
        } else {
            float* Cb = (float*)Cv;
#pragma unroll
            for (int j = 0; j < 4; j++) {
                const int col = col0 + ncol0 + j * 16 + m;
                const float bi = bias[col];
#pragma unroll
                for (int r = 0; r < 4; r++)
                    Cb[(size_t)(rbase + r) * ldC + col] = acc[i][j][r] + bi;
            }
        }
    }
}

// ---------------------------------------------------------------------------
// Fused projections, all-128-tile where possible:
//   blocks [0,448):   v 128x128 (64 x 7)
//   blocks [448,704): q/k cols 0-255 as 128x128 (64 x 2 x {q,k})
//   blocks [704,832): q/k cols 256-319 remainder as 128x64 (64 x {q,k})
// ---------------------------------------------------------------------------
__global__ __launch_bounds__(256)
void proj_kernel(const us* __restrict__ Xq, const us* __restrict__ Xk,
                 const us* __restrict__ Xv,
                 const us* __restrict__ Wqt, const us* __restrict__ Wkt,
                 const us* __restrict__ Wvt,
                 const float* __restrict__ bq, const float* __restrict__ bk,
                 const float* __restrict__ bv,
                 us* __restrict__ qbuf, us* __restrict__ kbuf,
                 us* __restrict__ vbuf)
{
    __shared__ us As[128 * 64];
    __shared__ us Bs[128 * 64];
    const int b = blockIdx.x;
    if (b < 448) {
        gemm128_core(Xv, Wvt, bv, vbuf, D_MODEL, N_CAT, 1,
                     (b & 63) << 7, (b >> 6) << 7, As, Bs);
    } else if (b < 704) {
        const int idx = b - 448;
        const int bx = idx & 63;
        const int rest = idx >> 6;                   // 0..3
        const int cy = rest & 1, z = rest >> 1;
        gemm128_core(z ? Xk : Xq, z ? Wkt : Wqt, z ? bk : bq,
                     z ? kbuf : qbuf, D_MODEL, NQK, 1,
                     bx << 7, cy << 7, As, Bs);
    } else {
        const int idx = b - 704;
        const int bx = idx & 63;
        const int z  = idx >> 6;                     // 0,1
        gemm64_core(z ? Xk : Xq, z ? Wkt : Wqt, z ? bk : bq,
                    z ? kbuf : qbuf, D_MODEL, NQK,
                    bx << 7, 256, As, Bs);
    }
}

// out gemm: [8192][896] bf16 @ [896][1024] -> fp32
__global__ __launch_bounds__(256)
void gemm_out(const us* __restrict__ ab, const us* __restrict__ Wct,
              const float* __restrict__ bc, float* __restrict__ out)
{
    __shared__ us As[128 * 64];
    __shared__ us Bs[128 * 64];
    gemm128_core(ab, Wct, bc, out, N_CAT, D_MODEL, 0,
                 (int)(blockIdx.x << 7), (int)(blockIdx.y << 7), As, Bs);
}

// ---------------------------------------------------------------------------
// Attention kernel, (slab, head) decomposition, sigma-interleaved kv layout,
// T14 async v-staging: v global loads ISSUE at kernel top (fly concurrently
// with k/q staging, drained by the same barrier-1), held in VGPRs through
// the scores phase, ds_written after barrier-2. Removes the serial HBM
// round-trip that sat between scores and PV.
// ---------------------------------------------------------------------------
template<int ROWS>
__global__ __launch_bounds__(256)
void attn_kernel(const us* __restrict__ qb, const us* __restrict__ kb,
                 const us* __restrict__ vb,
                 const float* __restrict__ Ws, const float* __restrict__ bs,
                 us* __restrict__ ab, int hbase)
{
    __shared__ uu    kv[ROWS * 36];     // kslab (score phase) = vslab (PV phase)
    __shared__ uu    qslab[64 * 32];
    __shared__ float sab[64 * 36];      // scores, overwritten by attn weights

    constexpr int VT = (ROWS * 8 + 255) / 256;   // 95->3, 312->10

    const int tid  = threadIdx.x;
    const int wave = tid >> 6;
    const int lane = tid & 63;
    const int j    = lane & 31;
    const int half = lane >> 5;
    const int h    = hbase + blockIdx.y;
    const int s    = subhead_of(h);
    const int ld   = (s <= 1) ? 0 : (s - 1);     // log2(dilation)
    const int d    = 1 << ld;
    const int ml0  = blockIdx.x * 64;
    const int l0   = ml0 & 4095;
    const int bm   = ml0 - l0;
    const int W    = 64 + 31 * d;
    const int Bseg = W >> ld;                    // W/d (exact)

    // ---- stage k (sigma layout) + q (gload_lds, linear) ----
    const uu4* kg4 = (const uu4*)kb;   // row stride 40 uu4
    const uu4* qg4 = (const uu4*)qb;   // row stride 40 uu4
    for (int idx = tid; idx < W * 8; idx += 256) {
        int r = idx >> 3, c4 = idx & 7;
        int src = l0 - 16 * d + r;
        src = src < 0 ? 0 : (src > 4095 ? 4095 : src);
        int slot = (r & (d - 1)) * Bseg + (r >> ld);
        *(uu4*)&kv[slot * 36 + c4 * 4] = kg4[(size_t)(bm + src) * 40 + s * 8 + c4];
    }
#pragma unroll
    for (int it = 0; it < 2; it++) {
        const int idx = it * 256 + tid;
        const int r = idx >> 3, c4 = idx & 7;
        load16(&qslab[(it * 256 + wave * 64) * 4],
               &qg4[(size_t)(ml0 + r) * 40 + s * 8 + c4]);
    }

    // ---- T14: issue v loads NOW (overlap k/q staging + barrier drain) ----
    const uu4* vg4 = (const uu4*)vb;   // row stride 112 uu4
    uu4 vreg[VT];
#pragma unroll
    for (int it = 0; it < VT; it++) {
        const int idx = it * 256 + tid;
        if (idx < W * 8) {
            const int r = idx >> 3, c4 = idx & 7;
            int src = l0 - 16 * d + r;
            src = src < 0 ? 0 : (src > 4095 ? 4095 : src);
            vreg[it] = vg4[(size_t)(bm + src) * 112 + h * 8 + c4];
        }
    }
    __syncthreads();

    // ---- scores -> sab (rows wave-private) ----
#pragma unroll
    for (int i = 0; i < 8; i++) {
        const int p = wave * 16 + i * 2 + half;
        const int sb = (p & (d - 1)) * Bseg + (p >> ld);
        const uu4* k4 = (const uu4*)&kv[(sb + j) * 36];
        const uu4* q4 = (const uu4*)&qslab[p * 32];
        float acc = 0.f;
#pragma unroll
        for (int q = 0; q < 8; q++) {
            uu4 kd = k4[q];
            uu4 qd = q4[q];
            acc = fmaf(blo(kd.x), blo(qd.x), acc); acc = fmaf(bhi(kd.x), bhi(qd.x), acc);
            acc = fmaf(blo(kd.y), blo(qd.y), acc); acc = fmaf(bhi(kd.y), bhi(qd.y), acc);
            acc = fmaf(blo(kd.z), blo(qd.z), acc); acc = fmaf(bhi(kd.z), bhi(qd.z), acc);
            acc = fmaf(blo(kd.w), blo(qd.w), acc); acc = fmaf(bhi(kd.w), bhi(qd.w), acc);
        }
        sab[p * 36 + j] = acc * 0.125f;
    }
    __syncthreads();    // all waves done reading kslab -> safe to overwrite

    // ---- v ds_writes from registers (loads long since landed) ----
#pragma unroll
    for (int it = 0; it < VT; it++) {
        const int idx = it * 256 + tid;
        if (idx < W * 8) {
            const int r = idx >> 3, c4 = idx & 7;
            const int slot = (r & (d - 1)) * Bseg + (r >> ld);
            *(uu4*)&kv[slot * 36 + c4 * 4] = vreg[it];
        }
    }
    float wsr[32];
#pragma unroll
    for (int k = 0; k < 32; k++) wsr[k] = Ws[(size_t)h * 1024 + k * 32 + j];
    const float bsv = bs[h * 32 + j];

    // ---- resample + softmax -> sab overwrite (wave-private rows) ----
#pragma unroll
    for (int i = 0; i < 8; i++) {
        const int p = wave * 16 + i * 2 + half;
        const float4* s4 = (const float4*)&sab[p * 36];
        float acc = bsv;
#pragma unroll
        for (int q = 0; q < 8; q++) {
            float4 v = s4[q];
            acc = fmaf(v.x, wsr[q * 4 + 0], acc);
            acc = fmaf(v.y, wsr[q * 4 + 1], acc);
            acc = fmaf(v.z, wsr[q * 4 + 2], acc);
            acc = fmaf(v.w, wsr[q * 4 + 3], acc);
        }
        float mx = acc;
#pragma unroll
        for (int off = 16; off > 0; off >>= 1) mx = fmaxf(mx, __shfl_xor(mx, off, 64));
        float ex = __expf(acc - mx);
        float sum = ex;
#pragma unroll
        for (int off = 16; off > 0; off >>= 1) sum += __shfl_xor(sum, off, 64);
        sab[p * 36 + j] = ex / sum;
    }
    __syncthreads();   // vslab fully staged

    // ---- PV: 8 positions per pass, at-weights batched 8-at-a-time ----
    const int o = lane >> 3;     // position octet
    const int c = lane & 7;      // channel chunk (4 dwords = 8 channels)
#pragma unroll
    for (int pass = 0; pass < 2; pass++) {
        const int p  = wave * 16 + pass * 8 + o;
        const int ml = ml0 + p;
        const int sbp = (p & (d - 1)) * Bseg + (p >> ld);
        float a0 = 0.f, a1 = 0.f, a2 = 0.f, a3 = 0.f;
        float a4 = 0.f, a5 = 0.f, a6 = 0.f, a7 = 0.f;
#pragma unroll
        for (int mg = 0; mg < 4; mg++) {
            const float4 wA = *(const float4*)&sab[p * 36 + mg * 8];
            const float4 wB = *(const float4*)&sab[p * 36 + mg * 8 + 4];
            const float at8[8] = {wA.x, wA.y, wA.z, wA.w, wB.x, wB.y, wB.z, wB.w};
#pragma unroll
            for (int m2 = 0; m2 < 8; m2++) {
                const float at = at8[m2];
                uu4 vd = *(const uu4*)&kv[(sbp + mg * 8 + m2) * 36 + c * 4];
                a0 = fmaf(blo(vd.x), at, a0); a1 = fmaf(bhi(vd.x), at, a1);
                a2 = fmaf(blo(vd.y), at, a2); a3 = fmaf(bhi(vd.y), at, a3);
                a4 = fmaf(blo(vd.z), at, a4); a5 = fmaf(bhi(vd.z), at, a5);
                a6 = fmaf(blo(vd.w), at, a6); a7 = fmaf(bhi(vd.w), at, a7);
            }
        }
        uu4 od;
        od.x = pack2(a0, a1); od.y = pack2(a2, a3);
        od.z = pack2(a4, a5); od.w = pack2(a6, a7);
        *(uu4*)&((uu*)ab)[(size_t)ml * 448 + h * 32 + c * 4] = od;
    }
}

// ---------------------------------------------------------------------------
extern "C" void kernel_launch(void* const* d_in, const int* in_sizes, int n_in,
                              void* d_out, int out_size, void* d_ws, size_t ws_size,
                              hipStream_t stream)
{
    const float* query = (const float*)d_in[0];
    const float* key   = (const float*)d_in[1];
    const float* value = (const float*)d_in[2];
    const float* Wq    = (const float*)d_in[3];
    const float* bq    = (const float*)d_in[4];
    const float* Wk    = (const float*)d_in[5];
    const float* bk    = (const float*)d_in[6];
    const float* Wv    = (const float*)d_in[7];
    const float* bv    = (const float*)d_in[8];
    const float* Ws    = (const float*)d_in[9];
    const float* bs    = (const float*)d_in[10];
    const float* Wc    = (const float*)d_in[11];
    const float* bc    = (const float*)d_in[12];
    float* out = (float*)d_out;

    // workspace carve (bf16 elements). ab aliases Xq (Xq dead after q gemm).
    us* w = (us*)d_ws;
    us* Xq  = w;                          // 8192*1024
    us* ab  = w;                          // 8192*896 (alias of Xq)
    us* Xk  = Xq  + (size_t)M_ROWS * D_MODEL;
    us* Xv  = Xk  + (size_t)M_ROWS * D_MODEL;
    us* Wqt = Xv  + (size_t)M_ROWS * D_MODEL;           // [320][1024]
    us* Wkt = Wqt + (size_t)SUBHEADS * D_INT * D_MODEL;
    us* Wvt = Wkt + (size_t)SUBHEADS * D_INT * D_MODEL; // [896][1024]
    us* Wct = Wvt + (size_t)HEADS * D_INT * D_MODEL;    // [1024][896]
    us* qbuf = Wct + (size_t)D_MODEL * N_CAT;           // [8192][320]
    us* kbuf = qbuf + (size_t)M_ROWS * NQK;
    us* vbuf = kbuf + (size_t)M_ROWS * NQK;             // [8192][896]

    dim3 blk(256);

    // prep: grid-stride q/k/v casts + weight transposes in one launch
    prep_kernel<<<dim3(CAST_BLK + 2432), blk, 0, stream>>>(
        (const float4*)query, (const float4*)key, (const float4*)value,
        Wq, Wk, Wv, Wc, Xq, Xk, Xv, Wqt, Wkt, Wvt, Wct);

    // fused q/k/v projections: 448 v-128 + 256 qk-128 + 128 qk-64 = 832
    proj_kernel<<<dim3(832), blk, 0, stream>>>(
        Xq, Xk, Xv, Wqt, Wkt, Wvt, bq, bk, bv, qbuf, kbuf, vbuf);

    // attention, one head per block:
    //   heads 0-9 (d=1, W=95):   grid 1280, LDS 31.1 KB -> 5 blocks/CU
    //   heads 10-13 (W<=312):    grid 512,  LDS 62.3 KB -> 2 blocks/CU
    attn_kernel<95><<<dim3(M_ROWS / 64, 10), blk, 0, stream>>>(
        qbuf, kbuf, vbuf, Ws, bs, ab, 0);
    attn_kernel<312><<<dim3(M_ROWS / 64, 4), blk, 0, stream>>>(
        qbuf, kbuf, vbuf, Ws, bs, ab, 10);

    // out gemm: [8192][896] @ [896][1024] -> fp32 (128x128 tile)
    gemm_out<<<dim3(M_ROWS / 128, D_MODEL / 128), blk, 0, stream>>>(
        ab, Wct, bc, out);
}

// Round 9
// 268.028 us; speedup vs baseline: 1.1352x; 1.0374x over previous
//
#include <hip/hip_runtime.h>
#include <math.h>

#define D_MODEL 1024
#define D_INT   64
#define KW      32
#define L_SEQ   4096
#define SUBHEADS 5
#define HEADS   14
#define M_ROWS  8192
#define N_CAT   896
#define NQK     320          // SUBHEADS*64

typedef unsigned short us;
typedef unsigned int   uu;
typedef __attribute__((ext_vector_type(2))) unsigned int uu2;
typedef __attribute__((ext_vector_type(4))) unsigned int uu4;
typedef __attribute__((ext_vector_type(8))) short bf16x8_t;
typedef __attribute__((ext_vector_type(4))) float f32x4_t;

__device__ __forceinline__ float u2f(uu u) {
    float f; __builtin_memcpy(&f, &u, 4); return f;
}
__device__ __forceinline__ float blo(uu u) { return u2f(u << 16); }
__device__ __forceinline__ float bhi(uu u) { return u2f(u & 0xffff0000u); }
__device__ __forceinline__ us f2b(float f) {
    uu u; __builtin_memcpy(&u, &f, 4);
    u += 0x7fffu + ((u >> 16) & 1u);
    return (us)(u >> 16);
}
__device__ __forceinline__ uu pack2(float a, float b) {
    return (uu)f2b(a) | ((uu)f2b(b) << 16);
}
// hardware packed cvt: RNE, bit-identical to pack2
__device__ __forceinline__ uu cvtpk(float a, float b) {
    uu r;
    asm("v_cvt_pk_bf16_f32 %0, %1, %2" : "=v"(r) : "v"(a), "v"(b));
    return r;
}
__device__ __forceinline__ void load16(void* lds, const void* g) {
    __builtin_amdgcn_global_load_lds(
        (const __attribute__((address_space(1))) unsigned int*)g,
        (__attribute__((address_space(3))) unsigned int*)lds, 16, 0, 0);
}
__device__ __forceinline__ int subhead_of(int h) {
    return (h < 5) ? 0 : (h < 10) ? 1 : (h < 12) ? 2 : (h == 12) ? 3 : 4;
}

// ---------------------------------------------------------------------------
// Prep mega-kernel.
//   blocks [0,3072): q/k/v fp32->bf16 cast, ILP-forced:
//     8 unit-stride f32x4 NT loads ALL issued before any consume (32 VGPRs
//     of loads in flight -> no serial load-wait-store chains), then 8
//     cvt+8B stores. NT on loads: single-use data, keep L3 for the bf16
//     outputs that proj re-reads.
//   blocks [3072,5504): 32x32 weight transpose-casts (NT reads).
// ---------------------------------------------------------------------------
#define CAST_BLK 3072
__global__ __launch_bounds__(256)
void prep_kernel(const float* __restrict__ q, const float* __restrict__ k,
                 const float* __restrict__ v,
                 const float* __restrict__ Wq, const float* __restrict__ Wk,
                 const float* __restrict__ Wv, const float* __restrict__ Wc,
                 us* __restrict__ Xq, us* __restrict__ Xk, us* __restrict__ Xv,
                 us* __restrict__ Wqt, us* __restrict__ Wkt,
                 us* __restrict__ Wvt, us* __restrict__ Wct)
{
    __shared__ float t[32][33];
    const int tid = threadIdx.x;
    const int b = blockIdx.x;

    if (b < CAST_BLK) {
        const int arr = b >> 10;              // 0,1,2
        const int blk = b & 1023;
        const f32x4_t* s = (const f32x4_t*)((arr == 0) ? q : (arr == 1) ? k : v);
        uu2* d = (uu2*)((arr == 0) ? Xq : (arr == 1) ? Xk : Xv);
        const int i0 = blk * 2048 + tid;      // block covers 2048 float4
        f32x4_t xs[8];
#pragma unroll
        for (int kk = 0; kk < 8; kk++)
            xs[kk] = __builtin_nontemporal_load(&s[i0 + kk * 256]);
#pragma unroll
        for (int kk = 0; kk < 8; kk++) {
            uu2 o;
            o.x = cvtpk(xs[kk].x, xs[kk].y);
            o.y = cvtpk(xs[kk].z, xs[kk].w);
            d[i0 + kk * 256] = o;
        }
        return;
    }

    int g = b - CAST_BLK;
    const float* S; us* D; int K, N;
    if (g < 640) {
        if (g < 320) { S = Wq; D = Wqt; } else { S = Wk; D = Wkt; g -= 320; }
        K = 1024; N = 64;
    } else if (g < 1536) {
        g -= 640; S = Wv; D = Wvt; K = 1024; N = 64;
    } else {
        g -= 1536; S = Wc; D = Wct; K = 896; N = 1024;
    }
    const int nkx = K >> 5;
    const int kx = g % nkx;
    const int rest = g / nkx;
    const int ny = rest % (N >> 5);
    const int z  = rest / (N >> 5);
    const int k0 = kx * 32, n0 = ny * 32;
    S += (size_t)z * K * N;
    D += (size_t)z * K * N;
    const int tx = tid & 31, ty = tid >> 5;
#pragma unroll
    for (int r = 0; r < 32; r += 8)
        t[r + ty][tx] = __builtin_nontemporal_load(&S[(size_t)(k0 + r + ty) * N + n0 + tx]);
    __syncthreads();
#pragma unroll
    for (int r = 0; r < 32; r += 8)
        D[(size_t)(n0 + r + ty) * K + k0 + tx] = f2b(t[tx][r + ty]);
}

// ---------------------------------------------------------------------------
// 128x64-tile GEMM core (BK=64, XOR-swizzled LDS, global_load_lds 16B)
// kept only for the q/k 64-col remainder (cols 256-319).
// ---------------------------------------------------------------------------
__device__ __forceinline__
void gemm64_core(const us* __restrict__ A, const us* __restrict__ Bt,
                 const float* __restrict__ bias, us* __restrict__ C,
                 int K, int ldC, int row0, int col0, us* As, us* Bs)
{
    const int tid = threadIdx.x, w = tid >> 6, lane = tid & 63;
    const int m = lane & 15, quad = lane >> 4;
    const int sr = lane >> 3;
    const int scs = (lane & 7) ^ sr;

    f32x4_t z4 = {0.f, 0.f, 0.f, 0.f};
    f32x4_t acc[2][4] = {{z4, z4, z4, z4}, {z4, z4, z4, z4}};

    for (int k0 = 0; k0 < K; k0 += 64) {
#pragma unroll
        for (int p = 0; p < 4; p++) {
            const int r = w * 32 + p * 8 + sr;
            load16(&As[(w * 32 + p * 8) * 64], A + (size_t)(row0 + r) * K + k0 + scs * 8);
        }
#pragma unroll
        for (int p = 0; p < 2; p++) {
            const int r = w * 16 + p * 8 + sr;
            load16(&Bs[(w * 16 + p * 8) * 64], Bt + (size_t)(col0 + r) * K + k0 + scs * 8);
        }
        __syncthreads();
#pragma unroll
        for (int ks = 0; ks < 2; ks++) {
            const int slot = ((ks * 4 + quad) ^ (m & 7)) * 8;
            bf16x8_t a0 = *(const bf16x8_t*)&As[(w * 32 + m) * 64 + slot];
            bf16x8_t a1 = *(const bf16x8_t*)&As[(w * 32 + 16 + m) * 64 + slot];
#pragma unroll
            for (int t = 0; t < 4; t++) {
                bf16x8_t bb = *(const bf16x8_t*)&Bs[(t * 16 + m) * 64 + slot];
                acc[0][t] = __builtin_amdgcn_mfma_f32_16x16x32_bf16(a0, bb, acc[0][t], 0, 0, 0);
                acc[1][t] = __builtin_amdgcn_mfma_f32_16x16x32_bf16(a1, bb, acc[1][t], 0, 0, 0);
            }
        }
        __syncthreads();
    }

#pragma unroll
    for (int tm = 0; tm < 2; tm++) {
        const int rbase = row0 + w * 32 + tm * 16 + quad * 4;
#pragma unroll
        for (int t = 0; t < 4; t++) {
            const int col = col0 + t * 16 + m;
            const float bi = bias[col];
#pragma unroll
            for (int r = 0; r < 4; r++)
                C[(size_t)(rbase + r) * ldC + col] = f2b(acc[tm][t][r] + bi);
        }
    }
}

// ---------------------------------------------------------------------------
// 128x128-tile core (m97 structure)
// ---------------------------------------------------------------------------
__device__ __forceinline__
void gemm128_core(const us* __restrict__ A, const us* __restrict__ Bt,
                  const float* __restrict__ bias, void* __restrict__ Cv,
                  int K, int ldC, int outBf16, int row0, int col0,
                  us* As, us* Bs)
{
    const int tid = threadIdx.x, w = tid >> 6, lane = tid & 63;
    const int m = lane & 15, quad = lane >> 4;
    const int sr = lane >> 3;
    const int scs = (lane & 7) ^ sr;
    const int mrow0 = (w & 1) * 64, ncol0 = (w >> 1) * 64;

    f32x4_t z = {0.f, 0.f, 0.f, 0.f};
    f32x4_t acc[4][4] = {{z,z,z,z},{z,z,z,z},{z,z,z,z},{z,z,z,z}};

    for (int k0 = 0; k0 < K; k0 += 64) {
#pragma unroll
        for (int p = 0; p < 4; p++) {
            const int r = w * 32 + p * 8 + sr;
            load16(&As[(w * 32 + p * 8) * 64], A  + (size_t)(row0 + r) * K + k0 + scs * 8);
            load16(&Bs[(w * 32 + p * 8) * 64], Bt + (size_t)(col0 + r) * K + k0 + scs * 8);
        }
        __syncthreads();
#pragma unroll
        for (int ks = 0; ks < 2; ks++) {
            const int slot = ((ks * 4 + quad) ^ (m & 7)) * 8;
            bf16x8_t a[4], b[4];
#pragma unroll
            for (int t = 0; t < 4; t++) {
                a[t] = *(const bf16x8_t*)&As[(mrow0 + t * 16 + m) * 64 + slot];
                b[t] = *(const bf16x8_t*)&Bs[(ncol0 + t * 16 + m) * 64 + slot];
            }
#pragma unroll
            for (int i = 0; i < 4; i++)
#pragma unroll
                for (int j = 0; j < 4; j++)
                    acc[i][j] = __builtin_amdgcn_mfma_f32_16x16x32_bf16(a[i], b[j], acc[i][j], 0, 0, 0);
        }
        __syncthreads();
    }

#pragma unroll
    for (int i = 0; i < 4; i++) {
        const int rbase = row0 + mrow0 + i * 16 + quad * 4;
        if (outBf16) {
            us* Cb = (us*)Cv;
#pragma unroll
            for (int j = 0; j < 4; j++) {
                const int col = col0 + ncol0 + j * 16 + m;
                const float bi = bias[col];
#pragma unroll
                for (int r = 0; r < 4; r++)
                    Cb[(size_t)(rbase + r) * ldC + col] = f2b(acc[i][j][r] + bi);
            }
        } else {
            float* Cb = (float*)Cv;
#pragma unroll
            for (int j = 0; j < 4; j++) {
                const int col = col0 + ncol0 + j * 16 + m;
                const float bi = bias[col];
#pragma unroll
                for (int r = 0; r < 4; r++)
                    Cb[(size_t)(rbase + r) * ldC + col] = acc[i][j][r] + bi;
            }
        }
    }
}

// ---------------------------------------------------------------------------
// Fused projections, all-128-tile where possible:
//   blocks [0,448):   v 128x128 (64 x 7)
//   blocks [448,704): q/k cols 0-255 as 128x128 (64 x 2 x {q,k})
//   blocks [704,832): q/k cols 256-319 remainder as 128x64 (64 x {q,k})
// ---------------------------------------------------------------------------
__global__ __launch_bounds__(256)
void proj_kernel(const us* __restrict__ Xq, const us* __restrict__ Xk,
                 const us* __restrict__ Xv,
                 const us* __restrict__ Wqt, const us* __restrict__ Wkt,
                 const us* __restrict__ Wvt,
                 const float* __restrict__ bq, const float* __restrict__ bk,
                 const float* __restrict__ bv,
                 us* __restrict__ qbuf, us* __restrict__ kbuf,
                 us* __restrict__ vbuf)
{
    __shared__ us As[128 * 64];
    __shared__ us Bs[128 * 64];
    const int b = blockIdx.x;
    if (b < 448) {
        gemm128_core(Xv, Wvt, bv, vbuf, D_MODEL, N_CAT, 1,
                     (b & 63) << 7, (b >> 6) << 7, As, Bs);
    } else if (b < 704) {
        const int idx = b - 448;
        const int bx = idx & 63;
        const int rest = idx >> 6;                   // 0..3
        const int cy = rest & 1, z = rest >> 1;
        gemm128_core(z ? Xk : Xq, z ? Wkt : Wqt, z ? bk : bq,
                     z ? kbuf : qbuf, D_MODEL, NQK, 1,
                     bx << 7, cy << 7, As, Bs);
    } else {
        const int idx = b - 704;
        const int bx = idx & 63;
        const int z  = idx >> 6;                     // 0,1
        gemm64_core(z ? Xk : Xq, z ? Wkt : Wqt, z ? bk : bq,
                    z ? kbuf : qbuf, D_MODEL, NQK,
                    bx << 7, 256, As, Bs);
    }
}

// out gemm: [8192][896] bf16 @ [896][1024] -> fp32
__global__ __launch_bounds__(256)
void gemm_out(const us* __restrict__ ab, const us* __restrict__ Wct,
              const float* __restrict__ bc, float* __restrict__ out)
{
    __shared__ us As[128 * 64];
    __shared__ us Bs[128 * 64];
    gemm128_core(ab, Wct, bc, out, N_CAT, D_MODEL, 0,
                 (int)(blockIdx.x << 7), (int)(blockIdx.y << 7), As, Bs);
}

// ---------------------------------------------------------------------------
// Attention kernel, (slab, head) decomposition, sigma-interleaved kv layout,
// T14 async v-staging (v loads issued at top, ds_written after barrier-2).
// ---------------------------------------------------------------------------
template<int ROWS>
__global__ __launch_bounds__(256)
void attn_kernel(const us* __restrict__ qb, const us* __restrict__ kb,
                 const us* __restrict__ vb,
                 const float* __restrict__ Ws, const float* __restrict__ bs,
                 us* __restrict__ ab, int hbase)
{
    __shared__ uu    kv[ROWS * 36];     // kslab (score phase) = vslab (PV phase)
    __shared__ uu    qslab[64 * 32];
    __shared__ float sab[64 * 36];      // scores, overwritten by attn weights

    constexpr int VT = (ROWS * 8 + 255) / 256;   // 95->3, 312->10

    const int tid  = threadIdx.x;
    const int wave = tid >> 6;
    const int lane = tid & 63;
    const int j    = lane & 31;
    const int half = lane >> 5;
    const int h    = hbase + blockIdx.y;
    const int s    = subhead_of(h);
    const int ld   = (s <= 1) ? 0 : (s - 1);     // log2(dilation)
    const int d    = 1 << ld;
    const int ml0  = blockIdx.x * 64;
    const int l0   = ml0 & 4095;
    const int bm   = ml0 - l0;
    const int W    = 64 + 31 * d;
    const int Bseg = W >> ld;                    // W/d (exact)

    // ---- stage k (sigma layout) + q (gload_lds, linear) ----
    const uu4* kg4 = (const uu4*)kb;   // row stride 40 uu4
    const uu4* qg4 = (const uu4*)qb;   // row stride 40 uu4
    for (int idx = tid; idx < W * 8; idx += 256) {
        int r = idx >> 3, c4 = idx & 7;
        int src = l0 - 16 * d + r;
        src = src < 0 ? 0 : (src > 4095 ? 4095 : src);
        int slot = (r & (d - 1)) * Bseg + (r >> ld);
        *(uu4*)&kv[slot * 36 + c4 * 4] = kg4[(size_t)(bm + src) * 40 + s * 8 + c4];
    }
#pragma unroll
    for (int it = 0; it < 2; it++) {
        const int idx = it * 256 + tid;
        const int r = idx >> 3, c4 = idx & 7;
        load16(&qslab[(it * 256 + wave * 64) * 4],
               &qg4[(size_t)(ml0 + r) * 40 + s * 8 + c4]);
    }

    // ---- T14: issue v loads NOW (overlap k/q staging + barrier drain) ----
    const uu4* vg4 = (const uu4*)vb;   // row stride 112 uu4
    uu4 vreg[VT];
#pragma unroll
    for (int it = 0; it < VT; it++) {
        const int idx = it * 256 + tid;
        if (idx < W * 8) {
            const int r = idx >> 3, c4 = idx & 7;
            int src = l0 - 16 * d + r;
            src = src < 0 ? 0 : (src > 4095 ? 4095 : src);
            vreg[it] = vg4[(size_t)(bm + src) * 112 + h * 8 + c4];
        }
    }
    __syncthreads();

    // ---- scores -> sab (rows wave-private) ----
#pragma unroll
    for (int i = 0; i < 8; i++) {
        const int p = wave * 16 + i * 2 + half;
        const int sb = (p & (d - 1)) * Bseg + (p >> ld);
        const uu4* k4 = (const uu4*)&kv[(sb + j) * 36];
        const uu4* q4 = (const uu4*)&qslab[p * 32];
        float acc = 0.f;
#pragma unroll
        for (int q = 0; q < 8; q++) {
            uu4 kd = k4[q];
            uu4 qd = q4[q];
            acc = fmaf(blo(kd.x), blo(qd.x), acc); acc = fmaf(bhi(kd.x), bhi(qd.x), acc);
            acc = fmaf(blo(kd.y), blo(qd.y), acc); acc = fmaf(bhi(kd.y), bhi(qd.y), acc);
            acc = fmaf(blo(kd.z), blo(qd.z), acc); acc = fmaf(bhi(kd.z), bhi(qd.z), acc);
            acc = fmaf(blo(kd.w), blo(qd.w), acc); acc = fmaf(bhi(kd.w), bhi(qd.w), acc);
        }
        sab[p * 36 + j] = acc * 0.125f;
    }
    __syncthreads();    // all waves done reading kslab -> safe to overwrite

    // ---- v ds_writes from registers (loads long since landed) ----
#pragma unroll
    for (int it = 0; it < VT; it++) {
        const int idx = it * 256 + tid;
        if (idx < W * 8) {
            const int r = idx >> 3, c4 = idx & 7;
            const int slot = (r & (d - 1)) * Bseg + (r >> ld);
            *(uu4*)&kv[slot * 36 + c4 * 4] = vreg[it];
        }
    }
    float wsr[32];
#pragma unroll
    for (int k = 0; k < 32; k++) wsr[k] = Ws[(size_t)h * 1024 + k * 32 + j];
    const float bsv = bs[h * 32 + j];

    // ---- resample + softmax -> sab overwrite (wave-private rows) ----
#pragma unroll
    for (int i = 0; i < 8; i++) {
        const int p = wave * 16 + i * 2 + half;
        const float4* s4 = (const float4*)&sab[p * 36];
        float acc = bsv;
#pragma unroll
        for (int q = 0; q < 8; q++) {
            float4 v = s4[q];
            acc = fmaf(v.x, wsr[q * 4 + 0], acc);
            acc = fmaf(v.y, wsr[q * 4 + 1], acc);
            acc = fmaf(v.z, wsr[q * 4 + 2], acc);
            acc = fmaf(v.w, wsr[q * 4 + 3], acc);
        }
        float mx = acc;
#pragma unroll
        for (int off = 16; off > 0; off >>= 1) mx = fmaxf(mx, __shfl_xor(mx, off, 64));
        float ex = __expf(acc - mx);
        float sum = ex;
#pragma unroll
        for (int off = 16; off > 0; off >>= 1) sum += __shfl_xor(sum, off, 64);
        sab[p * 36 + j] = ex / sum;
    }
    __syncthreads();   // vslab fully staged

    // ---- PV: 8 positions per pass, at-weights batched 8-at-a-time ----
    const int o = lane >> 3;     // position octet
    const int c = lane & 7;      // channel chunk (4 dwords = 8 channels)
#pragma unroll
    for (int pass = 0; pass < 2; pass++) {
        const int p  = wave * 16 + pass * 8 + o;
        const int ml = ml0 + p;
        const int sbp = (p & (d - 1)) * Bseg + (p >> ld);
        float a0 = 0.f, a1 = 0.f, a2 = 0.f, a3 = 0.f;
        float a4 = 0.f, a5 = 0.f, a6 = 0.f, a7 = 0.f;
#pragma unroll
        for (int mg = 0; mg < 4; mg++) {
            const float4 wA = *(const float4*)&sab[p * 36 + mg * 8];
            const float4 wB = *(const float4*)&sab[p * 36 + mg * 8 + 4];
            const float at8[8] = {wA.x, wA.y, wA.z, wA.w, wB.x, wB.y, wB.z, wB.w};
#pragma unroll
            for (int m2 = 0; m2 < 8; m2++) {
                const float at = at8[m2];
                uu4 vd = *(const uu4*)&kv[(sbp + mg * 8 + m2) * 36 + c * 4];
                a0 = fmaf(blo(vd.x), at, a0); a1 = fmaf(bhi(vd.x), at, a1);
                a2 = fmaf(blo(vd.y), at, a2); a3 = fmaf(bhi(vd.y), at, a3);
                a4 = fmaf(blo(vd.z), at, a4); a5 = fmaf(bhi(vd.z), at, a5);
                a6 = fmaf(blo(vd.w), at, a6); a7 = fmaf(bhi(vd.w), at, a7);
            }
        }
        uu4 od;
        od.x = pack2(a0, a1); od.y = pack2(a2, a3);
        od.z = pack2(a4, a5); od.w = pack2(a6, a7);
        *(uu4*)&((uu*)ab)[(size_t)ml * 448 + h * 32 + c * 4] = od;
    }
}

// ---------------------------------------------------------------------------
extern "C" void kernel_launch(void* const* d_in, const int* in_sizes, int n_in,
                              void* d_out, int out_size, void* d_ws, size_t ws_size,
                              hipStream_t stream)
{
    const float* query = (const float*)d_in[0];
    const float* key   = (const float*)d_in[1];
    const float* value = (const float*)d_in[2];
    const float* Wq    = (const float*)d_in[3];
    const float* bq    = (const float*)d_in[4];
    const float* Wk    = (const float*)d_in[5];
    const float* bk    = (const float*)d_in[6];
    const float* Wv    = (const float*)d_in[7];
    const float* bv    = (const float*)d_in[8];
    const float* Ws    = (const float*)d_in[9];
    const float* bs    = (const float*)d_in[10];
    const float* Wc    = (const float*)d_in[11];
    const float* bc    = (const float*)d_in[12];
    float* out = (float*)d_out;

    // workspace carve (bf16 elements). ab aliases Xq (Xq dead after q gemm).
    us* w = (us*)d_ws;
    us* Xq  = w;                          // 8192*1024
    us* ab  = w;                          // 8192*896 (alias of Xq)
    us* Xk  = Xq  + (size_t)M_ROWS * D_MODEL;
    us* Xv  = Xk  + (size_t)M_ROWS * D_MODEL;
    us* Wqt = Xv  + (size_t)M_ROWS * D_MODEL;           // [320][1024]
    us* Wkt = Wqt + (size_t)SUBHEADS * D_INT * D_MODEL;
    us* Wvt = Wkt + (size_t)SUBHEADS * D_INT * D_MODEL; // [896][1024]
    us* Wct = Wvt + (size_t)HEADS * D_INT * D_MODEL;    // [1024][896]
    us* qbuf = Wct + (size_t)D_MODEL * N_CAT;           // [8192][320]
    us* kbuf = qbuf + (size_t)M_ROWS * NQK;
    us* vbuf = kbuf + (size_t)M_ROWS * NQK;             // [8192][896]

    dim3 blk(256);

    // prep: ILP-forced q/k/v casts + weight transposes in one launch
    prep_kernel<<<dim3(CAST_BLK + 2432), blk, 0, stream>>>(
        query, key, value,
        Wq, Wk, Wv, Wc, Xq, Xk, Xv, Wqt, Wkt, Wvt, Wct);

    // fused q/k/v projections: 448 v-128 + 256 qk-128 + 128 qk-64 = 832
    proj_kernel<<<dim3(832), blk, 0, stream>>>(
        Xq, Xk, Xv, Wqt, Wkt, Wvt, bq, bk, bv, qbuf, kbuf, vbuf);

    // attention, one head per block:
    //   heads 0-9 (d=1, W=95):   grid 1280, LDS 31.1 KB -> 5 blocks/CU
    //   heads 10-13 (W<=312):    grid 512,  LDS 62.3 KB -> 2 blocks/CU
    attn_kernel<95><<<dim3(M_ROWS / 64, 10), blk, 0, stream>>>(
        qbuf, kbuf, vbuf, Ws, bs, ab, 0);
    attn_kernel<312><<<dim3(M_ROWS / 64, 4), blk, 0, stream>>>(
        qbuf, kbuf, vbuf, Ws, bs, ab, 10);

    // out gemm: [8192][896] @ [896][1024] -> fp32 (128x128 tile)
    gemm_out<<<dim3(M_ROWS / 128, D_MODEL / 128), blk, 0, stream>>>(
        ab, Wct, bc, out);
}

// Round 10
// 262.045 us; speedup vs baseline: 1.1612x; 1.0228x over previous
//
#include <hip/hip_runtime.h>
#include <math.h>

#define D_MODEL 1024
#define D_INT   64
#define KW      32
#define L_SEQ   4096
#define SUBHEADS 5
#define HEADS   14
#define M_ROWS  8192
#define N_CAT   896
#define NQK     320          // SUBHEADS*64

typedef unsigned short us;
typedef unsigned int   uu;
typedef __attribute__((ext_vector_type(2))) unsigned int uu2;
typedef __attribute__((ext_vector_type(4))) unsigned int uu4;
typedef __attribute__((ext_vector_type(8))) short bf16x8_t;
typedef __attribute__((ext_vector_type(4))) float f32x4_t;

__device__ __forceinline__ float u2f(uu u) {
    float f; __builtin_memcpy(&f, &u, 4); return f;
}
__device__ __forceinline__ float blo(uu u) { return u2f(u << 16); }
__device__ __forceinline__ float bhi(uu u) { return u2f(u & 0xffff0000u); }
__device__ __forceinline__ us f2b(float f) {
    uu u; __builtin_memcpy(&u, &f, 4);
    u += 0x7fffu + ((u >> 16) & 1u);
    return (us)(u >> 16);
}
__device__ __forceinline__ uu pack2(float a, float b) {
    return (uu)f2b(a) | ((uu)f2b(b) << 16);
}
// hardware packed cvt: RNE, bit-identical to pack2
__device__ __forceinline__ uu cvtpk(float a, float b) {
    uu r;
    asm("v_cvt_pk_bf16_f32 %0, %1, %2" : "=v"(r) : "v"(a), "v"(b));
    return r;
}
__device__ __forceinline__ void load16(void* lds, const void* g) {
    __builtin_amdgcn_global_load_lds(
        (const __attribute__((address_space(1))) unsigned int*)g,
        (__attribute__((address_space(3))) unsigned int*)lds, 16, 0, 0);
}
__device__ __forceinline__ int subhead_of(int h) {
    return (h < 5) ? 0 : (h < 10) ? 1 : (h < 12) ? 2 : (h == 12) ? 3 : 4;
}

// ---------------------------------------------------------------------------
// Prep mega-kernel (unchanged from round 9).
// ---------------------------------------------------------------------------
#define CAST_BLK 3072
__global__ __launch_bounds__(256)
void prep_kernel(const float* __restrict__ q, const float* __restrict__ k,
                 const float* __restrict__ v,
                 const float* __restrict__ Wq, const float* __restrict__ Wk,
                 const float* __restrict__ Wv, const float* __restrict__ Wc,
                 us* __restrict__ Xq, us* __restrict__ Xk, us* __restrict__ Xv,
                 us* __restrict__ Wqt, us* __restrict__ Wkt,
                 us* __restrict__ Wvt, us* __restrict__ Wct)
{
    __shared__ float t[32][33];
    const int tid = threadIdx.x;
    const int b = blockIdx.x;

    if (b < CAST_BLK) {
        const int arr = b >> 10;              // 0,1,2
        const int blk = b & 1023;
        const f32x4_t* s = (const f32x4_t*)((arr == 0) ? q : (arr == 1) ? k : v);
        uu2* d = (uu2*)((arr == 0) ? Xq : (arr == 1) ? Xk : Xv);
        const int i0 = blk * 2048 + tid;      // block covers 2048 float4
        f32x4_t xs[8];
#pragma unroll
        for (int kk = 0; kk < 8; kk++)
            xs[kk] = __builtin_nontemporal_load(&s[i0 + kk * 256]);
#pragma unroll
        for (int kk = 0; kk < 8; kk++) {
            uu2 o;
            o.x = cvtpk(xs[kk].x, xs[kk].y);
            o.y = cvtpk(xs[kk].z, xs[kk].w);
            d[i0 + kk * 256] = o;
        }
        return;
    }

    int g = b - CAST_BLK;
    const float* S; us* D; int K, N;
    if (g < 640) {
        if (g < 320) { S = Wq; D = Wqt; } else { S = Wk; D = Wkt; g -= 320; }
        K = 1024; N = 64;
    } else if (g < 1536) {
        g -= 640; S = Wv; D = Wvt; K = 1024; N = 64;
    } else {
        g -= 1536; S = Wc; D = Wct; K = 896; N = 1024;
    }
    const int nkx = K >> 5;
    const int kx = g % nkx;
    const int rest = g / nkx;
    const int ny = rest % (N >> 5);
    const int z  = rest / (N >> 5);
    const int k0 = kx * 32, n0 = ny * 32;
    S += (size_t)z * K * N;
    D += (size_t)z * K * N;
    const int tx = tid & 31, ty = tid >> 5;
#pragma unroll
    for (int r = 0; r < 32; r += 8)
        t[r + ty][tx] = __builtin_nontemporal_load(&S[(size_t)(k0 + r + ty) * N + n0 + tx]);
    __syncthreads();
#pragma unroll
    for (int r = 0; r < 32; r += 8)
        D[(size_t)(n0 + r + ty) * K + k0 + tx] = f2b(t[tx][r + ty]);
}

// ---------------------------------------------------------------------------
// 128x64-tile GEMM core, 8 WAVES (512 thr). Wave tile 32x32, acc[2][2]
// (16 AGPR). Same XOR-swizzled LDS layout (row&7 == sr invariant holds).
// ---------------------------------------------------------------------------
__device__ __forceinline__
void gemm64_core(const us* __restrict__ A, const us* __restrict__ Bt,
                 const float* __restrict__ bias, us* __restrict__ C,
                 int K, int ldC, int row0, int col0, us* As, us* Bs)
{
    const int tid = threadIdx.x, w = tid >> 6, lane = tid & 63;
    const int m = lane & 15, quad = lane >> 4;
    const int sr = lane >> 3;
    const int scs = (lane & 7) ^ sr;
    const int mrow0 = (w & 3) * 32, ncol0 = (w >> 2) * 32;

    f32x4_t z4 = {0.f, 0.f, 0.f, 0.f};
    f32x4_t acc[2][2] = {{z4, z4}, {z4, z4}};

    for (int k0 = 0; k0 < K; k0 += 64) {
#pragma unroll
        for (int p = 0; p < 2; p++) {
            const int r = w * 16 + p * 8 + sr;
            load16(&As[(w * 16 + p * 8) * 64], A + (size_t)(row0 + r) * K + k0 + scs * 8);
        }
        {
            const int r = w * 8 + sr;
            load16(&Bs[(w * 8) * 64], Bt + (size_t)(col0 + r) * K + k0 + scs * 8);
        }
        __syncthreads();
#pragma unroll
        for (int ks = 0; ks < 2; ks++) {
            const int slot = ((ks * 4 + quad) ^ (m & 7)) * 8;
            bf16x8_t a[2], b[2];
#pragma unroll
            for (int t = 0; t < 2; t++) {
                a[t] = *(const bf16x8_t*)&As[(mrow0 + t * 16 + m) * 64 + slot];
                b[t] = *(const bf16x8_t*)&Bs[(ncol0 + t * 16 + m) * 64 + slot];
            }
#pragma unroll
            for (int i = 0; i < 2; i++)
#pragma unroll
                for (int j = 0; j < 2; j++)
                    acc[i][j] = __builtin_amdgcn_mfma_f32_16x16x32_bf16(a[i], b[j], acc[i][j], 0, 0, 0);
        }
        __syncthreads();
    }

#pragma unroll
    for (int i = 0; i < 2; i++) {
        const int rbase = row0 + mrow0 + i * 16 + quad * 4;
#pragma unroll
        for (int j = 0; j < 2; j++) {
            const int col = col0 + ncol0 + j * 16 + m;
            const float bi = bias[col];
#pragma unroll
            for (int r = 0; r < 4; r++)
                C[(size_t)(rbase + r) * ldC + col] = f2b(acc[i][j][r] + bi);
        }
    }
}

// ---------------------------------------------------------------------------
// 128x128-tile core, 8 WAVES (512 thr). Wave tile 64x32, acc[4][2]
// (32 AGPR vs 64 at 4 waves) -> ~80 unified regs -> 4 blocks/CU (32 waves,
// full occupancy) instead of ~3 blocks at the 4-wave variant. Identical
// LDS layout, MFMA sequence, and per-output arithmetic order.
// ---------------------------------------------------------------------------
__device__ __forceinline__
void gemm128_core(const us* __restrict__ A, const us* __restrict__ Bt,
                  const float* __restrict__ bias, void* __restrict__ Cv,
                  int K, int ldC, int outBf16, int row0, int col0,
                  us* As, us* Bs)
{
    const int tid = threadIdx.x, w = tid >> 6, lane = tid & 63;
    const int m = lane & 15, quad = lane >> 4;
    const int sr = lane >> 3;
    const int scs = (lane & 7) ^ sr;
    const int mrow0 = (w & 1) * 64, ncol0 = (w >> 1) * 32;

    f32x4_t z = {0.f, 0.f, 0.f, 0.f};
    f32x4_t acc[4][2] = {{z,z},{z,z},{z,z},{z,z}};

    for (int k0 = 0; k0 < K; k0 += 64) {
#pragma unroll
        for (int p = 0; p < 2; p++) {
            const int r = w * 16 + p * 8 + sr;
            load16(&As[(w * 16 + p * 8) * 64], A  + (size_t)(row0 + r) * K + k0 + scs * 8);
            load16(&Bs[(w * 16 + p * 8) * 64], Bt + (size_t)(col0 + r) * K + k0 + scs * 8);
        }
        __syncthreads();
#pragma unroll
        for (int ks = 0; ks < 2; ks++) {
            const int slot = ((ks * 4 + quad) ^ (m & 7)) * 8;
            bf16x8_t a[4], b[2];
#pragma unroll
            for (int t = 0; t < 4; t++)
                a[t] = *(const bf16x8_t*)&As[(mrow0 + t * 16 + m) * 64 + slot];
#pragma unroll
            for (int t = 0; t < 2; t++)
                b[t] = *(const bf16x8_t*)&Bs[(ncol0 + t * 16 + m) * 64 + slot];
#pragma unroll
            for (int i = 0; i < 4; i++)
#pragma unroll
                for (int j = 0; j < 2; j++)
                    acc[i][j] = __builtin_amdgcn_mfma_f32_16x16x32_bf16(a[i], b[j], acc[i][j], 0, 0, 0);
        }
        __syncthreads();
    }

#pragma unroll
    for (int i = 0; i < 4; i++) {
        const int rbase = row0 + mrow0 + i * 16 + quad * 4;
        if (outBf16) {
            us* Cb = (us*)Cv;
#pragma unroll
            for (int j = 0; j < 2; j++) {
                const int col = col0 + ncol0 + j * 16 + m;
                const float bi = bias[col];
#pragma unroll
                for (int r = 0; r < 4; r++)
                    Cb[(size_t)(rbase + r) * ldC + col] = f2b(acc[i][j][r] + bi);
            }
        } else {
            float* Cb = (float*)Cv;
#pragma unroll
            for (int j = 0; j < 2; j++) {
                const int col = col0 + ncol0 + j * 16 + m;
                const float bi = bias[col];
#pragma unroll
                for (int r = 0; r < 4; r++)
                    Cb[(size_t)(rbase + r) * ldC + col] = acc[i][j][r] + bi;
            }
        }
    }
}

// ---------------------------------------------------------------------------
// Fused projections (512 threads/block):
//   blocks [0,448):   v 128x128 (64 x 7)
//   blocks [448,704): q/k cols 0-255 as 128x128 (64 x 2 x {q,k})
//   blocks [704,832): q/k cols 256-319 remainder as 128x64 (64 x {q,k})
// ---------------------------------------------------------------------------
__global__ __launch_bounds__(512)
void proj_kernel(const us* __restrict__ Xq, const us* __restrict__ Xk,
                 const us* __restrict__ Xv,
                 const us* __restrict__ Wqt, const us* __restrict__ Wkt,
                 const us* __restrict__ Wvt,
                 const float* __restrict__ bq, const float* __restrict__ bk,
                 const float* __restrict__ bv,
                 us* __restrict__ qbuf, us* __restrict__ kbuf,
                 us* __restrict__ vbuf)
{
    __shared__ us As[128 * 64];
    __shared__ us Bs[128 * 64];
    const int b = blockIdx.x;
    if (b < 448) {
        gemm128_core(Xv, Wvt, bv, vbuf, D_MODEL, N_CAT, 1,
                     (b & 63) << 7, (b >> 6) << 7, As, Bs);
    } else if (b < 704) {
        const int idx = b - 448;
        const int bx = idx & 63;
        const int rest = idx >> 6;                   // 0..3
        const int cy = rest & 1, z = rest >> 1;
        gemm128_core(z ? Xk : Xq, z ? Wkt : Wqt, z ? bk : bq,
                     z ? kbuf : qbuf, D_MODEL, NQK, 1,
                     bx << 7, cy << 7, As, Bs);
    } else {
        const int idx = b - 704;
        const int bx = idx & 63;
        const int z  = idx >> 6;                     // 0,1
        gemm64_core(z ? Xk : Xq, z ? Wkt : Wqt, z ? bk : bq,
                    z ? kbuf : qbuf, D_MODEL, NQK,
                    bx << 7, 256, As, Bs);
    }
}

// out gemm: [8192][896] bf16 @ [896][1024] -> fp32 (512 threads/block)
__global__ __launch_bounds__(512)
void gemm_out(const us* __restrict__ ab, const us* __restrict__ Wct,
              const float* __restrict__ bc, float* __restrict__ out)
{
    __shared__ us As[128 * 64];
    __shared__ us Bs[128 * 64];
    gemm128_core(ab, Wct, bc, out, N_CAT, D_MODEL, 0,
                 (int)(blockIdx.x << 7), (int)(blockIdx.y << 7), As, Bs);
}

// ---------------------------------------------------------------------------
// Attention kernel (unchanged from round 9): (slab, head) decomposition,
// sigma-interleaved kv layout, T14 async v-staging.
// ---------------------------------------------------------------------------
template<int ROWS>
__global__ __launch_bounds__(256)
void attn_kernel(const us* __restrict__ qb, const us* __restrict__ kb,
                 const us* __restrict__ vb,
                 const float* __restrict__ Ws, const float* __restrict__ bs,
                 us* __restrict__ ab, int hbase)
{
    __shared__ uu    kv[ROWS * 36];     // kslab (score phase) = vslab (PV phase)
    __shared__ uu    qslab[64 * 32];
    __shared__ float sab[64 * 36];      // scores, overwritten by attn weights

    constexpr int VT = (ROWS * 8 + 255) / 256;   // 95->3, 312->10

    const int tid  = threadIdx.x;
    const int wave = tid >> 6;
    const int lane = tid & 63;
    const int j    = lane & 31;
    const int half = lane >> 5;
    const int h    = hbase + blockIdx.y;
    const int s    = subhead_of(h);
    const int ld   = (s <= 1) ? 0 : (s - 1);     // log2(dilation)
    const int d    = 1 << ld;
    const int ml0  = blockIdx.x * 64;
    const int l0   = ml0 & 4095;
    const int bm   = ml0 - l0;
    const int W    = 64 + 31 * d;
    const int Bseg = W >> ld;                    // W/d (exact)

    // ---- stage k (sigma layout) + q (gload_lds, linear) ----
    const uu4* kg4 = (const uu4*)kb;   // row stride 40 uu4
    const uu4* qg4 = (const uu4*)qb;   // row stride 40 uu4
    for (int idx = tid; idx < W * 8; idx += 256) {
        int r = idx >> 3, c4 = idx & 7;
        int src = l0 - 16 * d + r;
        src = src < 0 ? 0 : (src > 4095 ? 4095 : src);
        int slot = (r & (d - 1)) * Bseg + (r >> ld);
        *(uu4*)&kv[slot * 36 + c4 * 4] = kg4[(size_t)(bm + src) * 40 + s * 8 + c4];
    }
#pragma unroll
    for (int it = 0; it < 2; it++) {
        const int idx = it * 256 + tid;
        const int r = idx >> 3, c4 = idx & 7;
        load16(&qslab[(it * 256 + wave * 64) * 4],
               &qg4[(size_t)(ml0 + r) * 40 + s * 8 + c4]);
    }

    // ---- T14: issue v loads NOW (overlap k/q staging + barrier drain) ----
    const uu4* vg4 = (const uu4*)vb;   // row stride 112 uu4
    uu4 vreg[VT];
#pragma unroll
    for (int it = 0; it < VT; it++) {
        const int idx = it * 256 + tid;
        if (idx < W * 8) {
            const int r = idx >> 3, c4 = idx & 7;
            int src = l0 - 16 * d + r;
            src = src < 0 ? 0 : (src > 4095 ? 4095 : src);
            vreg[it] = vg4[(size_t)(bm + src) * 112 + h * 8 + c4];
        }
    }
    __syncthreads();

    // ---- scores -> sab (rows wave-private) ----
#pragma unroll
    for (int i = 0; i < 8; i++) {
        const int p = wave * 16 + i * 2 + half;
        const int sb = (p & (d - 1)) * Bseg + (p >> ld);
        const uu4* k4 = (const uu4*)&kv[(sb + j) * 36];
        const uu4* q4 = (const uu4*)&qslab[p * 32];
        float acc = 0.f;
#pragma unroll
        for (int q = 0; q < 8; q++) {
            uu4 kd = k4[q];
            uu4 qd = q4[q];
            acc = fmaf(blo(kd.x), blo(qd.x), acc); acc = fmaf(bhi(kd.x), bhi(qd.x), acc);
            acc = fmaf(blo(kd.y), blo(qd.y), acc); acc = fmaf(bhi(kd.y), bhi(qd.y), acc);
            acc = fmaf(blo(kd.z), blo(qd.z), acc); acc = fmaf(bhi(kd.z), bhi(qd.z), acc);
            acc = fmaf(blo(kd.w), blo(qd.w), acc); acc = fmaf(bhi(kd.w), bhi(qd.w), acc);
        }
        sab[p * 36 + j] = acc * 0.125f;
    }
    __syncthreads();    // all waves done reading kslab -> safe to overwrite

    // ---- v ds_writes from registers (loads long since landed) ----
#pragma unroll
    for (int it = 0; it < VT; it++) {
        const int idx = it * 256 + tid;
        if (idx < W * 8) {
            const int r = idx >> 3, c4 = idx & 7;
            const int slot = (r & (d - 1)) * Bseg + (r >> ld);
            *(uu4*)&kv[slot * 36 + c4 * 4] = vreg[it];
        }
    }
    float wsr[32];
#pragma unroll
    for (int k = 0; k < 32; k++) wsr[k] = Ws[(size_t)h * 1024 + k * 32 + j];
    const float bsv = bs[h * 32 + j];

    // ---- resample + softmax -> sab overwrite (wave-private rows) ----
#pragma unroll
    for (int i = 0; i < 8; i++) {
        const int p = wave * 16 + i * 2 + half;
        const float4* s4 = (const float4*)&sab[p * 36];
        float acc = bsv;
#pragma unroll
        for (int q = 0; q < 8; q++) {
            float4 v = s4[q];
            acc = fmaf(v.x, wsr[q * 4 + 0], acc);
            acc = fmaf(v.y, wsr[q * 4 + 1], acc);
            acc = fmaf(v.z, wsr[q * 4 + 2], acc);
            acc = fmaf(v.w, wsr[q * 4 + 3], acc);
        }
        float mx = acc;
#pragma unroll
        for (int off = 16; off > 0; off >>= 1) mx = fmaxf(mx, __shfl_xor(mx, off, 64));
        float ex = __expf(acc - mx);
        float sum = ex;
#pragma unroll
        for (int off = 16; off > 0; off >>= 1) sum += __shfl_xor(sum, off, 64);
        sab[p * 36 + j] = ex / sum;
    }
    __syncthreads();   // vslab fully staged

    // ---- PV: 8 positions per pass, at-weights batched 8-at-a-time ----
    const int o = lane >> 3;     // position octet
    const int c = lane & 7;      // channel chunk (4 dwords = 8 channels)
#pragma unroll
    for (int pass = 0; pass < 2; pass++) {
        const int p  = wave * 16 + pass * 8 + o;
        const int ml = ml0 + p;
        const int sbp = (p & (d - 1)) * Bseg + (p >> ld);
        float a0 = 0.f, a1 = 0.f, a2 = 0.f, a3 = 0.f;
        float a4 = 0.f, a5 = 0.f, a6 = 0.f, a7 = 0.f;
#pragma unroll
        for (int mg = 0; mg < 4; mg++) {
            const float4 wA = *(const float4*)&sab[p * 36 + mg * 8];
            const float4 wB = *(const float4*)&sab[p * 36 + mg * 8 + 4];
            const float at8[8] = {wA.x, wA.y, wA.z, wA.w, wB.x, wB.y, wB.z, wB.w};
#pragma unroll
            for (int m2 = 0; m2 < 8; m2++) {
                const float at = at8[m2];
                uu4 vd = *(const uu4*)&kv[(sbp + mg * 8 + m2) * 36 + c * 4];
                a0 = fmaf(blo(vd.x), at, a0); a1 = fmaf(bhi(vd.x), at, a1);
                a2 = fmaf(blo(vd.y), at, a2); a3 = fmaf(bhi(vd.y), at, a3);
                a4 = fmaf(blo(vd.z), at, a4); a5 = fmaf(bhi(vd.z), at, a5);
                a6 = fmaf(blo(vd.w), at, a6); a7 = fmaf(bhi(vd.w), at, a7);
            }
        }
        uu4 od;
        od.x = pack2(a0, a1); od.y = pack2(a2, a3);
        od.z = pack2(a4, a5); od.w = pack2(a6, a7);
        *(uu4*)&((uu*)ab)[(size_t)ml * 448 + h * 32 + c * 4] = od;
    }
}

// ---------------------------------------------------------------------------
extern "C" void kernel_launch(void* const* d_in, const int* in_sizes, int n_in,
                              void* d_out, int out_size, void* d_ws, size_t ws_size,
                              hipStream_t stream)
{
    const float* query = (const float*)d_in[0];
    const float* key   = (const float*)d_in[1];
    const float* value = (const float*)d_in[2];
    const float* Wq    = (const float*)d_in[3];
    const float* bq    = (const float*)d_in[4];
    const float* Wk    = (const float*)d_in[5];
    const float* bk    = (const float*)d_in[6];
    const float* Wv    = (const float*)d_in[7];
    const float* bv    = (const float*)d_in[8];
    const float* Ws    = (const float*)d_in[9];
    const float* bs    = (const float*)d_in[10];
    const float* Wc    = (const float*)d_in[11];
    const float* bc    = (const float*)d_in[12];
    float* out = (float*)d_out;

    // workspace carve (bf16 elements). ab aliases Xq (Xq dead after q gemm).
    us* w = (us*)d_ws;
    us* Xq  = w;                          // 8192*1024
    us* ab  = w;                          // 8192*896 (alias of Xq)
    us* Xk  = Xq  + (size_t)M_ROWS * D_MODEL;
    us* Xv  = Xk  + (size_t)M_ROWS * D_MODEL;
    us* Wqt = Xv  + (size_t)M_ROWS * D_MODEL;           // [320][1024]
    us* Wkt = Wqt + (size_t)SUBHEADS * D_INT * D_MODEL;
    us* Wvt = Wkt + (size_t)SUBHEADS * D_INT * D_MODEL; // [896][1024]
    us* Wct = Wvt + (size_t)HEADS * D_INT * D_MODEL;    // [1024][896]
    us* qbuf = Wct + (size_t)D_MODEL * N_CAT;           // [8192][320]
    us* kbuf = qbuf + (size_t)M_ROWS * NQK;
    us* vbuf = kbuf + (size_t)M_ROWS * NQK;             // [8192][896]

    dim3 blk(256);
    dim3 blk512(512);

    // prep: ILP-forced q/k/v casts + weight transposes in one launch
    prep_kernel<<<dim3(CAST_BLK + 2432), blk, 0, stream>>>(
        query, key, value,
        Wq, Wk, Wv, Wc, Xq, Xk, Xv, Wqt, Wkt, Wvt, Wct);

    // fused q/k/v projections: 448 v-128 + 256 qk-128 + 128 qk-64 = 832
    proj_kernel<<<dim3(832), blk512, 0, stream>>>(
        Xq, Xk, Xv, Wqt, Wkt, Wvt, bq, bk, bv, qbuf, kbuf, vbuf);

    // attention, one head per block:
    //   heads 0-9 (d=1, W=95):   grid 1280, LDS 31.1 KB -> 5 blocks/CU
    //   heads 10-13 (W<=312):    grid 512,  LDS 62.3 KB -> 2 blocks/CU
    attn_kernel<95><<<dim3(M_ROWS / 64, 10), blk, 0, stream>>>(
        qbuf, kbuf, vbuf, Ws, bs, ab, 0);
    attn_kernel<312><<<dim3(M_ROWS / 64, 4), blk, 0, stream>>>(
        qbuf, kbuf, vbuf, Ws, bs, ab, 10);

    // out gemm: [8192][896] @ [896][1024] -> fp32 (128x128 tile)
    gemm_out<<<dim3(M_ROWS / 128, D_MODEL / 128), blk512, 0, stream>>>(
        ab, Wct, bc, out);
}